// Round 2
// baseline (312.682 us; speedup 1.0000x reference)
//
#include <hip/hip_runtime.h>
#include <hip/hip_bf16.h>

#define E_TOT 160000
#define NN    10000
#define EPB   32      // edges per block

typedef unsigned short ushortT;
typedef unsigned int   uintT;
typedef __attribute__((ext_vector_type(8))) short short8;
typedef __attribute__((ext_vector_type(4))) float f32x4;

__device__ __forceinline__ float sigmoidf_(float x) { return 1.0f / (1.0f + __expf(-x)); }
__device__ __forceinline__ float siluf_(float x) { return x * sigmoidf_(x); }

__device__ __forceinline__ ushortT f2b(float f) {
    union { float f; uintT u; } x; x.f = f;
    uintT r = x.u + 0x7fffu + ((x.u >> 16) & 1u);
    return (ushortT)(r >> 16);
}
__device__ __forceinline__ float b2f(ushortT h) {
    union { uintT u; float f; } x; x.u = ((uintT)h) << 16; return x.f;
}
__device__ __forceinline__ uintT pk2(float lo, float hi) {
    union { __hip_bfloat162 h; uintT u; } cv;
    cv.h = __float22bfloat162_rn(make_float2(lo, hi));
    return cv.u;
}
// 8 consecutive fp32 -> bf16 MFMA A-fragment (fallback path)
__device__ __forceinline__ short8 ldfrag(const float* p) {
    const float4 x = ((const float4*)p)[0];
    const float4 y = ((const float4*)p)[1];
    union { uintT u[4]; short8 s; } r;
    r.u[0] = pk2(x.x, x.y); r.u[1] = pk2(x.z, x.w);
    r.u[2] = pk2(y.x, y.y); r.u[3] = pk2(y.z, y.w);
    return r.s;
}

// ---- weight-table layout (ushort offsets within wt) ----
#define OFF_W1SO 0
#define OFF_W2SO 45056
#define OFF_W1DF 65536
#define OFF_W1G  68608
#define OFF_W1UP 70656
#define OFF_W2DF 71680
#define OFF_W2G  72704
#define OFF_W2UP 74752
#define WT_USH   75264

// ---- CSR workspace layout (bytes from ws base) ----
#define NOFF_OFF   56320000ULL
#define CUR_OFF    56360016ULL
#define WT_OFF     57040032ULL
#define WS_CSR     57190560ULL
#define NS16_OFF   57190560ULL              // bf16 node_s [10000][128]
#define WS_NS      59750560ULL
#define ES16_OFF   59750560ULL              // bf16 edge_s [160000][32]
#define WS_ES      69990560ULL

__device__ __forceinline__ bool idx_is64(const int* pi) {
    return (pi[1] | pi[3] | pi[5] | pi[7] | pi[9] | pi[11] | pi[13] | pi[15]) == 0;
}

// weight transpose helper (shared by setup_kernel and fallback prep_kernel)
__device__ __forceinline__ void weight_prep(
    int i,
    const float* __restrict__ W1so, const float* __restrict__ W2so,
    const float* __restrict__ W1d,  const float* __restrict__ W1f,
    const float* __restrict__ W1g,  const float* __restrict__ W1up,
    const float* __restrict__ W2d,  const float* __restrict__ W2f,
    const float* __restrict__ W2g,  const float* __restrict__ W2up,
    ushortT* __restrict__ ws)
{
    if (i < OFF_W2SO) {                        // W1soT [n=128][k=352], k<333 real
        int n = i / 352, k = i - n * 352;
        ws[i] = (k < 333) ? f2b(W1so[k * 128 + n]) : (ushortT)0;
    } else if (i < OFF_W1DF) {                 // W2soT [128][160], k<153 real
        int j = i - OFF_W2SO, n = j / 160, k = j - n * 160;
        ws[i] = (k < 153) ? f2b(W2so[k * 128 + n]) : (ushortT)0;
    } else if (i < OFF_W1G) {                  // W1dfT [48][64]: n<36 Wd, 36..38 Wf
        int j = i - OFF_W1DF, n = j / 64, k = j - n * 64;
        float v = 0.f;
        if (k < 36) { if (n < 36) v = W1d[k * 36 + n]; else if (n < 39) v = W1f[k * 3 + (n - 36)]; }
        ws[i] = f2b(v);
    } else if (i < OFF_W1UP) {                 // W1gT [16][128]
        int j = i - OFF_W1G, n = j / 128, k = j - n * 128;
        ws[i] = f2b(W1g[k * 16 + n]);
    } else if (i < OFF_W2DF) {                 // W1upT [16][64], k<36 real
        int j = i - OFF_W1UP, n = j / 64, k = j - n * 64;
        ws[i] = (k < 36) ? f2b(W1up[k * 16 + n]) : (ushortT)0;
    } else if (i < OFF_W2G) {                  // W2dfT [32][32]: n<16 Wd, 16..18 Wf; k<16
        int j = i - OFF_W2DF, n = j / 32, k = j - n * 32;
        float v = 0.f;
        if (k < 16) { if (n < 16) v = W2d[k * 16 + n]; else if (n < 19) v = W2f[k * 3 + (n - 16)]; }
        ws[i] = f2b(v);
    } else if (i < OFF_W2UP) {                 // W2gT [16][128]
        int j = i - OFF_W2G, n = j / 128, k = j - n * 128;
        ws[i] = f2b(W2g[k * 16 + n]);
    } else if (i < WT_USH) {                   // W2upT [16][32], k<16 real
        int j = i - OFF_W2UP, n = j / 32, k = j - n * 32;
        ws[i] = (k < 16) ? f2b(W2up[k * 16 + n]) : (ushortT)0;
    }
}

// CSR-mode combined setup: weight transpose + degree histogram + bf16 input tables.
// grid 625*256 = 160000 exactly. cur must be zeroed beforehand (memset).
__global__ __launch_bounds__(256) void setup_kernel(
    const float* __restrict__ W1so, const float* __restrict__ W2so,
    const float* __restrict__ W1d,  const float* __restrict__ W1f,
    const float* __restrict__ W1g,  const float* __restrict__ W1up,
    const float* __restrict__ W2d,  const float* __restrict__ W2f,
    const float* __restrict__ W2g,  const float* __restrict__ W2up,
    ushortT* __restrict__ ws,
    const void* __restrict__ eidx, int* __restrict__ cur,
    const float* __restrict__ node_s, const float* __restrict__ edge_s,
    ushortT* __restrict__ ns16, ushortT* __restrict__ es16)
{
    int i = blockIdx.x * 256 + threadIdx.x;
    // histogram
    {
        const int* pi = (const int*)eidx;
        const long long* pl = (const long long*)eidx;
        int r = idx_is64(pi) ? (int)pl[i] : pi[i];
        atomicAdd(&cur[r], 1);
    }
    // bf16 node_s table: 1,280,000 elems = 160,000 x 8
    if (ns16 && i < 160000) {
        float4 x = ((const float4*)node_s)[i * 2];
        float4 y = ((const float4*)node_s)[i * 2 + 1];
        uint4 st;
        st.x = pk2(x.x, x.y); st.y = pk2(x.z, x.w);
        st.z = pk2(y.x, y.y); st.w = pk2(y.z, y.w);
        ((uint4*)ns16)[i] = st;
    }
    // bf16 edge_s table: 5,120,000 elems = 160,000 x 32
    if (es16) {
        #pragma unroll
        for (int k = 0; k < 4; ++k) {
            float4 x = ((const float4*)edge_s)[i * 8 + 2 * k];
            float4 y = ((const float4*)edge_s)[i * 8 + 2 * k + 1];
            uint4 st;
            st.x = pk2(x.x, x.y); st.y = pk2(x.z, x.w);
            st.z = pk2(y.x, y.y); st.w = pk2(y.z, y.w);
            ((uint4*)es16)[i * 4 + k] = st;
        }
    }
    // weight transpose (first 75,264 threads)
    weight_prep(i, W1so, W2so, W1d, W1f, W1g, W1up, W2d, W2f, W2g, W2up, ws);
}

// fallback (non-CSR): weight transpose + zero d_out
__global__ __launch_bounds__(256) void prep_kernel(
    const float* __restrict__ W1so, const float* __restrict__ W2so,
    const float* __restrict__ W1d,  const float* __restrict__ W1f,
    const float* __restrict__ W1g,  const float* __restrict__ W1up,
    const float* __restrict__ W2d,  const float* __restrict__ W2f,
    const float* __restrict__ W2g,  const float* __restrict__ W2up,
    ushortT* __restrict__ ws, float* __restrict__ out)
{
    int i = blockIdx.x * 256 + threadIdx.x;    // grid 294*256 = 75264
    float4* o4 = (float4*)out;
    #pragma unroll
    for (int k = 0; k < 6; ++k) {
        int z = i + k * 75264;
        if (z < 440000) o4[z] = make_float4(0.f, 0.f, 0.f, 0.f);
    }
    weight_prep(i, W1so, W2so, W1d, W1f, W1g, W1up, W2d, W2f, W2g, W2up, ws);
}

// single block: exclusive scan of cur[10000] -> noff[10001]; re-zero cur.
// LDS-staged for coalesced global access.
__global__ __launch_bounds__(256) void scan_kernel(int* __restrict__ cur,
                                                   int* __restrict__ noff)
{
    __shared__ int buf[10000];
    __shared__ int partial[256];
    const int t = threadIdx.x;
    for (int i = t; i < NN; i += 256) buf[i] = cur[i];     // coalesced
    for (int i = t; i < NN; i += 256) cur[i] = 0;          // re-zero for edge alloc
    __syncthreads();
    const int base = t * 40;
    int s = 0;
    #pragma unroll
    for (int i = 0; i < 40; ++i) s += (base + i < NN) ? buf[base + i] : 0;
    partial[t] = s;
    __syncthreads();
    for (int o = 1; o < 256; o <<= 1) {
        int v = (t >= o) ? partial[t - o] : 0;
        __syncthreads();
        partial[t] += v;
        __syncthreads();
    }
    int run = (t == 0) ? 0 : partial[t - 1];
    #pragma unroll
    for (int i = 0; i < 40; ++i) {
        int gi = base + i;
        if (gi < NN) { int v = buf[gi]; noff[gi] = run; run += v; }
    }
    if (t == 255) noff[NN] = partial[255];
}

// one wave per node: FB rows are CSR-contiguous -> pure streaming read.
__global__ __launch_bounds__(256) void node_kernel(const ushortT* __restrict__ fb,
                                                   const int* __restrict__ noff,
                                                   float* __restrict__ out)
{
    const int w = threadIdx.x >> 6, l = threadIdx.x & 63;
    const int n = blockIdx.x * 4 + w;          // grid 2500 -> 10000 nodes
    if (l >= 44) return;                        // 44 lanes x 4 bf16 cols = 176
    const int s = noff[n], eend = noff[n + 1];
    float a0 = 0.f, a1 = 0.f, a2 = 0.f, a3 = 0.f;
    int idx = s;
    for (; idx + 2 <= eend; idx += 2) {
        uint2 p0 = *(const uint2*)(fb + (size_t)idx * 176 + l * 4);
        uint2 p1 = *(const uint2*)(fb + (size_t)(idx + 1) * 176 + l * 4);
        a0 += b2f((ushortT)(p0.x & 0xffff)); a1 += b2f((ushortT)(p0.x >> 16));
        a2 += b2f((ushortT)(p0.y & 0xffff)); a3 += b2f((ushortT)(p0.y >> 16));
        a0 += b2f((ushortT)(p1.x & 0xffff)); a1 += b2f((ushortT)(p1.x >> 16));
        a2 += b2f((ushortT)(p1.y & 0xffff)); a3 += b2f((ushortT)(p1.y >> 16));
    }
    if (idx < eend) {
        uint2 p0 = *(const uint2*)(fb + (size_t)idx * 176 + l * 4);
        a0 += b2f((ushortT)(p0.x & 0xffff)); a1 += b2f((ushortT)(p0.x >> 16));
        a2 += b2f((ushortT)(p0.y & 0xffff)); a3 += b2f((ushortT)(p0.y >> 16));
    }
    ((float4*)(out + (size_t)n * 176))[l] = make_float4(a0, a1, a2, a3);
}

#define MFMA(a, b, c) __builtin_amdgcn_mfma_f32_16x16x32_bf16((a), (b), (c), 0, 0, 0)

// LDS 27,136 B -> 6 blocks/CU (was 31,232 -> 5). Diet achieved by:
//  - v1A persistence E->J moved to registers (v1reg); LDS only used for the
//    wave-local E1-write -> E2-transposed-read, in-place with vhid2A in the
//    normbuf region (normbuf dead after barrier 4; disjoint tiles per wave).
//  - v1A-final (J->L) stride 24->16, overlaying fr+vfr2f (dead after barrier 6).
//  - attn/eposb in registers (te-group = 8 contiguous lanes -> __shfl).
__global__ __launch_bounds__(256, 6) void edge_kernel(
    const float* __restrict__ node_s, const float* __restrict__ node_v,
    const float* __restrict__ edge_s, const float* __restrict__ edge_v,
    const float* __restrict__ frames,
    const float* __restrict__ b1so, const float* __restrict__ b1g,
    const float* __restrict__ b2so, const float* __restrict__ b2g,
    const float* __restrict__ attW, const float* __restrict__ attb,
    const ushortT* __restrict__ wsc,
    const void* __restrict__ eidx, float* __restrict__ out,
    ushortT* __restrict__ fb, int* __restrict__ cur, const int* __restrict__ noff,
    const ushortT* __restrict__ ns16, const ushortT* __restrict__ es16,
    int csr)
{
    const ushortT* W1T   = wsc + OFF_W1SO;
    const ushortT* W2T   = wsc + OFF_W2SO;
    const ushortT* W1dfT = wsc + OFF_W1DF;
    const ushortT* W1gT  = wsc + OFF_W1G;
    const ushortT* W1upT = wsc + OFF_W1UP;
    const ushortT* W2dfT = wsc + OFF_W2DF;
    const ushortT* W2gT  = wsc + OFF_W2G;
    const ushortT* W2upT = wsc + OFF_W2UP;

    __shared__ __align__(16) char smem[27136];
    ushortT* mvA     = (ushortT*)smem;                 // [96][40] (A->B) | m2 [32][168] (D->L)
    ushortT* m2      = (ushortT*)smem;
    ushortT* vhidA   = (ushortT*)(smem + 10752);       // [96][40] (B->E) | s2s [32][136] (I->L)
    ushortT* s2s     = (ushortT*)(smem + 10752);
    ushortT* normbuf = (ushortT*)(smem + 19456);       // [32][72] (A->D')
    ushortT* v1s     = (ushortT*)(smem + 19456);       // [96][16] E scratch (in-place -> vhid2A)
    ushortT* vhid2A  = (ushortT*)(smem + 19456);       // [96][16] (G->J)
    float*   fr      = (float*)(smem + 24064);         // [32][9]  (A->H)
    float*   vfr2f   = (float*)(smem + 25216);         // [96][3]  (G->H)
    ushortT* v1f     = (ushortT*)(smem + 24064);       // [96][16] (J->L, overlays fr/vfr2f)

    const int t  = threadIdx.x;
    const int eg = blockIdx.x * EPB;
    const int w  = t >> 6, lane = t & 63, lq = lane >> 4, ln = lane & 15;
    const int te = t >> 3, tj = t & 7;     // 8 threads per edge
    const int p  = w & 1;

    const int* pi = (const int*)eidx;
    const long long* pl = (const long long*)eidx;
    const bool is64 = idx_is64(pi);

    int posr = 0;          // CSR slot (tj==0 lanes); broadcast via __shfl in Phase L
    float att_reg = 0.f;   // attention gate (all lanes of each te-group)

    // ==== Phase A: gathers (12-elem chunks: 3 float4 -> 6 packed uint) ====
    {
        const int nr = is64 ? (int)pl[eg + te] : pi[eg + te];
        const int nc = is64 ? (int)pl[E_TOT + eg + te] : pi[E_TOT + eg + te];
        #pragma unroll
        for (int mi = 0; mi < 2; ++mi) {
            if (mi == 1 && tj != 0) break;
            int m = (mi == 0) ? tj : 8;        // chunks 0..8; chunk = 4 c-cols x 3 sp
            const float* src;
            if (m < 4)       src = node_v + nr * 48 + 12 * m;
            else if (m == 4) src = edge_v + (eg + te) * 12;
            else             src = node_v + nc * 48 + 12 * (m - 5);
            float4 x = ((const float4*)src)[0];
            float4 y = ((const float4*)src)[1];
            float4 z = ((const float4*)src)[2];
            float v[12] = {x.x, x.y, x.z, x.w, y.x, y.y, y.z, y.w, z.x, z.y, z.z, z.w};
            int c0 = 4 * m;
            #pragma unroll
            for (int sp = 0; sp < 3; ++sp) {
                *(uintT*)(mvA + (sp * 32 + te) * 40 + c0)     = pk2(v[sp],     v[3 + sp]);
                *(uintT*)(mvA + (sp * 32 + te) * 40 + c0 + 2) = pk2(v[6 + sp], v[9 + sp]);
            }
        }
        #pragma unroll
        for (int k = 0; k < 2; ++k) {           // frames: 9 per edge
            int j = tj + k * 8;
            if (j < 9) fr[te * 9 + j] = frames[(eg + te) * 9 + j];
        }
        #pragma unroll
        for (int k = 0; k < 3; ++k) {           // normbuf cols 45..63 = 0
            int c = 45 + tj + k * 8;
            if (c < 64) normbuf[te * 72 + c] = 0;
        }
        if (t < 192) {                          // mvA cols 36..39 = 0
            int r = t >> 1, cc = 36 + ((t & 1) << 1);
            *(uintT*)(mvA + r * 40 + cc) = 0;
        }
        // CSR slot allocation: independent of all phases; atomic round-trip
        // overlaps the whole pipeline. Result stays in a register.
        if (csr && tj == 0) {
            posr = noff[nr] + atomicAdd(&cur[nr], 1);
        }
    }

    // ==== Phase A2 (pre-barrier): s_out1 global-K portion (ks 0..8) ====
    // A operands come from the bf16 gather tables (random L2), B from the weight
    // table (L2 stream) -- no LDS dependence. Accumulators live across barriers.
    const int klq = lq * 8;
    const int dn0 = w * 32 + ln, dn1 = dn0 + 16;
    const ushortT* b0p = W1T + dn0 * 352 + klq;
    const ushortT* b1p = W1T + dn1 * 352 + klq;
    f32x4 acc00 = {0,0,0,0}, acc01 = {0,0,0,0}, acc10 = {0,0,0,0}, acc11 = {0,0,0,0};
    float dbi0, dbi1;
    {
        const int e0 = ln, e1 = 16 + ln;
        int r0, c0, r1, c1;
        if (is64) {
            r0 = (int)pl[eg + e0]; r1 = (int)pl[eg + e1];
            c0 = (int)pl[E_TOT + eg + e0]; c1 = (int)pl[E_TOT + eg + e1];
        } else {
            r0 = pi[eg + e0]; r1 = pi[eg + e1];
            c0 = pi[E_TOT + eg + e0]; c1 = pi[E_TOT + eg + e1];
        }
        r0 *= 128; c0 *= 128; r1 *= 128; c1 *= 128;
        const int eb0 = (eg + e0) * 32, eb1 = (eg + e1) * 32;
        dbi0 = b1so[dn0]; dbi1 = b1so[dn1];
        #pragma unroll
        for (int ks = 0; ks < 9; ++ks) {
            short8 a0, a1;
            if (ks < 4) {
                if (ns16) {
                    a0 = *(const short8*)(ns16 + r0 + ks * 32 + klq);
                    a1 = *(const short8*)(ns16 + r1 + ks * 32 + klq);
                } else {
                    a0 = ldfrag(node_s + r0 + ks * 32 + klq);
                    a1 = ldfrag(node_s + r1 + ks * 32 + klq);
                }
            } else if (ks == 4) {
                if (es16) {
                    a0 = *(const short8*)(es16 + eb0 + klq);
                    a1 = *(const short8*)(es16 + eb1 + klq);
                } else {
                    a0 = ldfrag(edge_s + eb0 + klq);
                    a1 = ldfrag(edge_s + eb1 + klq);
                }
            } else {
                if (ns16) {
                    a0 = *(const short8*)(ns16 + c0 + (ks - 5) * 32 + klq);
                    a1 = *(const short8*)(ns16 + c1 + (ks - 5) * 32 + klq);
                } else {
                    a0 = ldfrag(node_s + c0 + (ks - 5) * 32 + klq);
                    a1 = ldfrag(node_s + c1 + (ks - 5) * 32 + klq);
                }
            }
            short8 b0 = *(const short8*)(b0p + ks * 32);
            short8 b1 = *(const short8*)(b1p + ks * 32);
            acc00 = MFMA(a0, b0, acc00); acc01 = MFMA(a0, b1, acc01);
            acc10 = MFMA(a1, b0, acc10); acc11 = MFMA(a1, b1, acc11);
        }
    }
    // pin the hoisted computation above barrier (1) so it can't be sunk back down
    asm volatile("" : "+v"(acc00), "+v"(acc01), "+v"(acc10), "+v"(acc11));
    __syncthreads();   // (1)

    // ==== Phase B: mvA[96xK36] @ W1dfT[48][64] -> vhidA[96][<=40] ====
    for (int u = w; u < 18; u += 4) {
        int mt = u / 3, nt = u - mt * 3;
        const ushortT* ap = mvA + (mt * 16 + ln) * 40 + lq * 8;
        const ushortT* bp = W1dfT + (nt * 16 + ln) * 64 + lq * 8;
        f32x4 acc = {0.f, 0.f, 0.f, 0.f};
        acc = MFMA(*(const short8*)ap, *(const short8*)bp, acc);
        short8 a2 = {0, 0, 0, 0, 0, 0, 0, 0};
        if (lq == 0) a2 = *(const short8*)(ap + 32);
        acc = MFMA(a2, *(const short8*)(bp + 32), acc);
        if (nt < 2 || ln < 8) {
            ushortT* op = vhidA + (mt * 16 + lq * 4) * 40 + nt * 16 + ln;
            op[0]   = f2b(acc[0]); op[40]  = f2b(acc[1]);
            op[80]  = f2b(acc[2]); op[120] = f2b(acc[3]);
        }
    }
    __syncthreads();   // (2)

    // ==== Phase C: v_norm1 + local1 -> normbuf cols 0..44 ====
    {
        #pragma unroll
        for (int k = 0; k < 5; ++k) {
            int h = tj + k * 8;
            if (h < 36) {
                float a0 = b2f(vhidA[te * 40 + h]);
                float a1 = b2f(vhidA[(32 + te) * 40 + h]);
                float a2 = b2f(vhidA[(64 + te) * 40 + h]);
                normbuf[te * 72 + h] = f2b(sqrtf(fmaf(a0, a0, fmaf(a1, a1, fmaf(a2, a2, 1e-8f)))));
            }
        }
        for (int i = t; i < 288; i += 256) {
            int e = i / 9, r = i - e * 9, a = r / 3, b = r - a * 3;
            float x = fr[e * 9 + b * 3 + 0] * b2f(vhidA[e * 40 + 36 + a])
                    + fr[e * 9 + b * 3 + 1] * b2f(vhidA[(32 + e) * 40 + 36 + a])
                    + fr[e * 9 + b * 3 + 2] * b2f(vhidA[(64 + e) * 40 + 36 + a]);
            normbuf[e * 72 + 36 + r] = f2b(x);
        }
    }
    __syncthreads();   // (3)

    // ==== Phase D': s_out1 normbuf K-steps (ks 9,10) + epilogue ====
    {
        const int e0 = ln, e1 = 16 + ln;
        #pragma unroll
        for (int ks = 9; ks < 11; ++ks) {
            short8 a0 = *(const short8*)(normbuf + e0 * 72 + (ks - 9) * 32 + klq);
            short8 a1 = *(const short8*)(normbuf + e1 * 72 + (ks - 9) * 32 + klq);
            short8 b0 = *(const short8*)(b0p + ks * 32);
            short8 b1 = *(const short8*)(b1p + ks * 32);
            acc00 = MFMA(a0, b0, acc00); acc01 = MFMA(a0, b1, acc01);
            acc10 = MFMA(a1, b0, acc10); acc11 = MFMA(a1, b1, acc11);
        }
        #pragma unroll
        for (int r = 0; r < 4; ++r) {
            int m0 = lq * 4 + r;
            m2[m0 * 168 + dn0]        = f2b(siluf_(acc00[r] + dbi0));
            m2[m0 * 168 + dn1]        = f2b(siluf_(acc01[r] + dbi1));
            m2[(16 + m0) * 168 + dn0] = f2b(siluf_(acc10[r] + dbi0));
            m2[(16 + m0) * 168 + dn1] = f2b(siluf_(acc11[r] + dbi1));
        }
    }
    __syncthreads();   // (4)

    // ==== Phase E+G (wave-local) ====
    float v1reg[2][4] = {{0.f,0.f,0.f,0.f},{0.f,0.f,0.f,0.f}};
    {
        f32x4 gacc = {0,0,0,0};
        {
            const ushortT* ap = m2 + (p * 16 + ln) * 168;
            const ushortT* bp = W1gT + ln * 128;
            #pragma unroll
            for (int ks = 0; ks < 4; ++ks)
                gacc = MFMA(*(const short8*)(ap + ks * 32 + lq * 8),
                            *(const short8*)(bp + ks * 32 + lq * 8), gacc);
        }
        float g1[4];
        {
            float bi = b1g[ln];
            #pragma unroll
            for (int r = 0; r < 4; ++r) g1[r] = sigmoidf_(gacc[r] + bi);
        }
        const ushortT* bpu = W1upT + ln * 64 + lq * 8;
        short8 bu1 = *(const short8*)bpu;
        short8 bu2 = *(const short8*)(bpu + 32);
        // E1: v1 = up(vhid1) * g1 -> registers + wave-local transpose scratch
        #pragma unroll
        for (int c = 0; c < 2; ++c) {
            if (c == 1 && w >= 2) break;
            int mt = w + c * 4;
            const ushortT* ap = vhidA + (mt * 16 + ln) * 40 + lq * 8;
            f32x4 acc = {0,0,0,0};
            acc = MFMA(*(const short8*)ap, bu1, acc);
            short8 a2 = {0, 0, 0, 0, 0, 0, 0, 0};
            if (lq == 0) a2 = *(const short8*)(ap + 32);
            acc = MFMA(a2, bu2, acc);
            #pragma unroll
            for (int r = 0; r < 4; ++r) {
                int row = mt * 16 + lq * 4 + r;
                float vv = acc[r] * g1[r];
                v1reg[c][r] = vv;
                v1s[row * 16 + ln] = f2b(vv);
            }
        }
        // E2/G: vhid2 = v1 @ W2dfT  (reads v1s tile, overwrites same tile in place)
        #pragma unroll
        for (int c = 0; c < 2; ++c) {
            if (c == 1 && w >= 2) break;
            int mt = w + c * 4;
            const ushortT* ap = v1s + (mt * 16 + ln) * 16 + lq * 8;
            short8 a = {0, 0, 0, 0, 0, 0, 0, 0};
            if (lq < 2) a = *(const short8*)ap;
            #pragma unroll
            for (int nt = 0; nt < 2; ++nt) {
                const ushortT* bp = W2dfT + (nt * 16 + ln) * 32 + lq * 8;
                f32x4 acc = {0,0,0,0};
                acc = MFMA(a, *(const short8*)bp, acc);
                if (nt == 0) {
                    ushortT* op = vhid2A + (mt * 16 + lq * 4) * 16 + ln;
                    op[0]  = f2b(acc[0]); op[16] = f2b(acc[1]);
                    op[32] = f2b(acc[2]); op[48] = f2b(acc[3]);
                } else if (ln < 3) {
                    float* op = vfr2f + (mt * 16 + lq * 4) * 3 + ln;
                    op[0] = acc[0]; op[3] = acc[1]; op[6] = acc[2]; op[9] = acc[3];
                }
            }
        }
    }
    __syncthreads();   // (5)

    // ==== Phase H: norm2 + local2 + zero pad into m2 cols 128..159 ====
    {
        #pragma unroll
        for (int k = 0; k < 2; ++k) {
            int i = t + k * 256, e = i >> 4, h = i & 15;
            float a0 = b2f(vhid2A[e * 16 + h]);
            float a1 = b2f(vhid2A[(32 + e) * 16 + h]);
            float a2 = b2f(vhid2A[(64 + e) * 16 + h]);
            m2[e * 168 + 128 + h] = f2b(sqrtf(fmaf(a0, a0, fmaf(a1, a1, fmaf(a2, a2, 1e-8f)))));
        }
        for (int i = t; i < 288; i += 256) {
            int e = i / 9, r = i - e * 9, a = r / 3, b = r - a * 3;
            float x = fr[e * 9 + b * 3 + 0] * vfr2f[e * 3 + a]
                    + fr[e * 9 + b * 3 + 1] * vfr2f[(32 + e) * 3 + a]
                    + fr[e * 9 + b * 3 + 2] * vfr2f[(64 + e) * 3 + a];
            m2[e * 168 + 144 + r] = f2b(x);
        }
        if (tj) m2[te * 168 + 152 + tj] = 0;
    }
    __syncthreads();   // (6)

    // ==== Phase I: s_out2 = m2[32][160] @ W2soT -> s2s (silu) ====
    {
        f32x4 acc00i = {0,0,0,0}, acc01i = {0,0,0,0}, acc10i = {0,0,0,0}, acc11i = {0,0,0,0};
        const ushortT* a0p = m2 + ln * 168 + lq * 8;
        const ushortT* a1p = m2 + (16 + ln) * 168 + lq * 8;
        const ushortT* b0pi = W2T + (w * 32 + ln) * 160 + lq * 8;
        const ushortT* b1pi = W2T + (w * 32 + 16 + ln) * 160 + lq * 8;
        #pragma unroll
        for (int ks = 0; ks < 5; ++ks) {
            short8 a0 = *(const short8*)(a0p + ks * 32);
            short8 a1 = *(const short8*)(a1p + ks * 32);
            short8 b0 = *(const short8*)(b0pi + ks * 32);
            short8 b1 = *(const short8*)(b1pi + ks * 32);
            acc00i = MFMA(a0, b0, acc00i); acc01i = MFMA(a0, b1, acc01i);
            acc10i = MFMA(a1, b0, acc10i); acc11i = MFMA(a1, b1, acc11i);
        }
        const int n0 = w * 32 + ln, n1 = n0 + 16;
        float bi0 = b2so[n0], bi1 = b2so[n1];
        #pragma unroll
        for (int r = 0; r < 4; ++r) {
            int m0 = lq * 4 + r;
            s2s[m0 * 136 + n0]        = f2b(siluf_(acc00i[r] + bi0));
            s2s[m0 * 136 + n1]        = f2b(siluf_(acc01i[r] + bi1));
            s2s[(16 + m0) * 136 + n0] = f2b(siluf_(acc10i[r] + bi0));
            s2s[(16 + m0) * 136 + n1] = f2b(siluf_(acc11i[r] + bi1));
        }
    }
    __syncthreads();   // (7)

    // ==== Phase J (wave-local) + attention ====
    {
        f32x4 gacc = {0,0,0,0};
        {
            const ushortT* ap = s2s + (p * 16 + ln) * 136;
            const ushortT* bp = W2gT + ln * 128;
            #pragma unroll
            for (int ks = 0; ks < 4; ++ks)
                gacc = MFMA(*(const short8*)(ap + ks * 32 + lq * 8),
                            *(const short8*)(bp + ks * 32 + lq * 8), gacc);
        }
        float g2[4];
        {
            float bi = b2g[ln];
            #pragma unroll
            for (int r = 0; r < 4; ++r) g2[r] = sigmoidf_(gacc[r] + bi);
        }
        const ushortT* bpu = W2upT + ln * 32 + lq * 8;
        short8 bu = *(const short8*)bpu;
        #pragma unroll
        for (int c = 0; c < 2; ++c) {
            if (c == 1 && w >= 2) break;
            int mt = w + c * 4;
            const ushortT* ap = vhid2A + (mt * 16 + ln) * 16 + lq * 8;
            short8 a = {0, 0, 0, 0, 0, 0, 0, 0};
            if (lq < 2) a = *(const short8*)ap;
            f32x4 acc = {0,0,0,0};
            acc = MFMA(a, bu, acc);
            #pragma unroll
            for (int r = 0; r < 4; ++r) {
                int row = mt * 16 + lq * 4 + r;
                float vfin = v1reg[c][r] + acc[r] * g2[r];
                v1f[row * 16 + ln] = f2b(vfin);
            }
        }
        {
            float sum = 0.f;
            int c0 = tj * 16;
            #pragma unroll
            for (int c = c0; c < c0 + 16; ++c)
                sum = fmaf(b2f(m2[te * 168 + c]) + b2f(s2s[te * 136 + c]), attW[c], sum);
            sum += __shfl_xor(sum, 4);
            sum += __shfl_xor(sum, 2);
            sum += __shfl_xor(sum, 1);
            att_reg = sigmoidf_(sum + attb[0]);   // all 8 lanes of the group
        }
    }
    __syncthreads();   // (8)

    // ==== Phase L: per-edge output ====
    {
        const float at = att_reg;
        if (csr) {
            const int pos = __shfl(posr, lane & 56);
            ushortT* fbe = fb + (size_t)pos * 176;
            #pragma unroll
            for (int k = 0; k < 11; ++k) {
                int j = 2 * tj + 16 * k;
                float v0, v1;
                if (j < 128) {
                    v0 = (b2f(m2[te * 168 + j])     + b2f(s2s[te * 136 + j]))     * at;
                    v1 = (b2f(m2[te * 168 + j + 1]) + b2f(s2s[te * 136 + j + 1])) * at;
                } else {
                    int r = j - 128;
                    int o0 = r / 3,        sp0 = r - o0 * 3;
                    int o1 = (r + 1) / 3,  sp1 = (r + 1) - o1 * 3;
                    v0 = b2f(v1f[(sp0 * 32 + te) * 16 + o0]);
                    v1 = b2f(v1f[(sp1 * 32 + te) * 16 + o1]);
                }
                *(uintT*)(fbe + j) = pk2(v0, v1);
            }
        } else {
            const int nr = is64 ? (int)pl[eg + te] : pi[eg + te];
            const int orow = nr * 176;
            #pragma unroll
            for (int k = 0; k < 22; ++k) {
                int j = tj + k * 8;
                float val;
                if (j < 128) {
                    val = (b2f(m2[te * 168 + j]) + b2f(s2s[te * 136 + j])) * at;
                } else {
                    int r = j - 128, o = r / 3, sp = r - o * 3;
                    val = b2f(v1f[(sp * 32 + te) * 16 + o]);
                }
                atomicAdd(&out[orow + j], val);
            }
        }
    }
}

extern "C" void kernel_launch(void* const* d_in, const int* in_sizes, int n_in,
                              void* d_out, int out_size, void* d_ws, size_t ws_size,
                              hipStream_t stream) {
    const float* node_s = (const float*)d_in[0];
    const float* node_v = (const float*)d_in[1];
    const float* edge_s = (const float*)d_in[2];
    const float* edge_v = (const float*)d_in[3];
    const float* frames = (const float*)d_in[4];
    const float* W1d  = (const float*)d_in[5];
    const float* W1f  = (const float*)d_in[6];
    const float* W1so = (const float*)d_in[7];
    const float* b1so = (const float*)d_in[8];
    const float* W1up = (const float*)d_in[9];
    const float* W1g  = (const float*)d_in[10];
    const float* b1g  = (const float*)d_in[11];
    const float* W2d  = (const float*)d_in[12];
    const float* W2f  = (const float*)d_in[13];
    const float* W2so = (const float*)d_in[14];
    const float* b2so = (const float*)d_in[15];
    const float* W2up = (const float*)d_in[16];
    const float* W2g  = (const float*)d_in[17];
    const float* b2g  = (const float*)d_in[18];
    const float* attW = (const float*)d_in[19];
    const float* attb = (const float*)d_in[20];
    const void*  eidx = d_in[21];

    float* out = (float*)d_out;
    char* ws = (char*)d_ws;

    int mode = 0;
    if (ws_size >= WS_ES)       mode = 3;
    else if (ws_size >= WS_NS)  mode = 2;
    else if (ws_size >= WS_CSR) mode = 1;
    const int csr = (mode >= 1);

    ushortT* wt    = csr ? (ushortT*)(ws + WT_OFF)  : (ushortT*)ws;
    ushortT* fbuf  = csr ? (ushortT*)ws             : nullptr;
    int*     noff  = csr ? (int*)(ws + NOFF_OFF)    : nullptr;
    int*     cur   = csr ? (int*)(ws + CUR_OFF)     : nullptr;
    ushortT* ns16  = (mode >= 2) ? (ushortT*)(ws + NS16_OFF) : nullptr;
    ushortT* es16  = (mode >= 3) ? (ushortT*)(ws + ES16_OFF) : nullptr;

    if (csr) {
        hipMemsetAsync(cur, 0, NN * sizeof(int), stream);
        setup_kernel<<<625, 256, 0, stream>>>(
            W1so, W2so, W1d, W1f, W1g, W1up, W2d, W2f, W2g, W2up,
            wt, eidx, cur, node_s, edge_s, ns16, es16);
        scan_kernel<<<1, 256, 0, stream>>>(cur, noff);
    } else {
        prep_kernel<<<294, 256, 0, stream>>>(W1so, W2so, W1d, W1f, W1g, W1up,
                                             W2d, W2f, W2g, W2up, wt, out);
    }

    edge_kernel<<<E_TOT / EPB, 256, 0, stream>>>(
        node_s, node_v, edge_s, edge_v, frames,
        b1so, b1g, b2so, b2g, attW, attb,
        (const ushortT*)wt, eidx, out, fbuf, cur, noff, ns16, es16, csr);

    if (csr) {
        node_kernel<<<2500, 256, 0, stream>>>((const ushortT*)fbuf, noff, out);
    }
}

// Round 3
// 277.836 us; speedup vs baseline: 1.1254x; 1.1254x over previous
//
#include <hip/hip_runtime.h>
#include <hip/hip_bf16.h>

#define E_TOT 160000
#define NN    10000
#define EPB   32      // edges per block

typedef unsigned short ushortT;
typedef unsigned int   uintT;
typedef __attribute__((ext_vector_type(8))) short short8;
typedef __attribute__((ext_vector_type(4))) float f32x4;

__device__ __forceinline__ float sigmoidf_(float x) { return 1.0f / (1.0f + __expf(-x)); }
__device__ __forceinline__ float siluf_(float x) { return x * sigmoidf_(x); }

__device__ __forceinline__ ushortT f2b(float f) {
    union { float f; uintT u; } x; x.f = f;
    uintT r = x.u + 0x7fffu + ((x.u >> 16) & 1u);
    return (ushortT)(r >> 16);
}
__device__ __forceinline__ float b2f(ushortT h) {
    union { uintT u; float f; } x; x.u = ((uintT)h) << 16; return x.f;
}
__device__ __forceinline__ uintT pk2(float lo, float hi) {
    union { __hip_bfloat162 h; uintT u; } cv;
    cv.h = __float22bfloat162_rn(make_float2(lo, hi));
    return cv.u;
}
// 8 consecutive fp32 -> bf16 MFMA A-fragment
__device__ __forceinline__ short8 ldfrag(const float* p) {
    const float4 x = ((const float4*)p)[0];
    const float4 y = ((const float4*)p)[1];
    union { uintT u[4]; short8 s; } r;
    r.u[0] = pk2(x.x, x.y); r.u[1] = pk2(x.z, x.w);
    r.u[2] = pk2(y.x, y.y); r.u[3] = pk2(y.z, y.w);
    return r.s;
}

// ---- weight-table layout (ushort offsets within wt) ----
#define OFF_W1SO 0
#define OFF_W2SO 45056
#define OFF_W1DF 65536
#define OFF_W1G  68608
#define OFF_W1UP 70656
#define OFF_W2DF 71680
#define OFF_W2G  72704
#define OFF_W2UP 74752
#define WT_USH   75264

// ---- CSR workspace layout (bytes from ws base) ----
#define NOFF_OFF   56320000ULL
#define CUR_OFF    56360016ULL
#define WT_OFF     57040032ULL
#define WS_CSR     57190560ULL
#define NS16_OFF   57190560ULL              // bf16 node_s [10000][128]
#define WS_NS      59750560ULL
#define PR_OFF     59750560ULL              // bf16 Pr = node_s@W1so[0:128]   [10000][128]
#define PC_OFF     62310560ULL              // bf16 Pc = node_s@W1so[160:288] [10000][128]
#define PRE_END    64870560ULL

__device__ __forceinline__ bool idx_is64(const int* pi) {
    return (pi[1] | pi[3] | pi[5] | pi[7] | pi[9] | pi[11] | pi[13] | pi[15]) == 0;
}

// weight transpose helper (shared by setup_kernel and fallback prep_kernel)
__device__ __forceinline__ void weight_prep(
    int i,
    const float* __restrict__ W1so, const float* __restrict__ W2so,
    const float* __restrict__ W1d,  const float* __restrict__ W1f,
    const float* __restrict__ W1g,  const float* __restrict__ W1up,
    const float* __restrict__ W2d,  const float* __restrict__ W2f,
    const float* __restrict__ W2g,  const float* __restrict__ W2up,
    ushortT* __restrict__ ws)
{
    if (i < OFF_W2SO) {                        // W1soT [n=128][k=352], k<333 real
        int n = i / 352, k = i - n * 352;
        ws[i] = (k < 333) ? f2b(W1so[k * 128 + n]) : (ushortT)0;
    } else if (i < OFF_W1DF) {                 // W2soT [128][160], k<153 real
        int j = i - OFF_W2SO, n = j / 160, k = j - n * 160;
        ws[i] = (k < 153) ? f2b(W2so[k * 128 + n]) : (ushortT)0;
    } else if (i < OFF_W1G) {                  // W1dfT [48][64]: n<36 Wd, 36..38 Wf
        int j = i - OFF_W1DF, n = j / 64, k = j - n * 64;
        float v = 0.f;
        if (k < 36) { if (n < 36) v = W1d[k * 36 + n]; else if (n < 39) v = W1f[k * 3 + (n - 36)]; }
        ws[i] = f2b(v);
    } else if (i < OFF_W1UP) {                 // W1gT [16][128]
        int j = i - OFF_W1G, n = j / 128, k = j - n * 128;
        ws[i] = f2b(W1g[k * 16 + n]);
    } else if (i < OFF_W2DF) {                 // W1upT [16][64], k<36 real
        int j = i - OFF_W1UP, n = j / 64, k = j - n * 64;
        ws[i] = (k < 36) ? f2b(W1up[k * 16 + n]) : (ushortT)0;
    } else if (i < OFF_W2G) {                  // W2dfT [32][32]: n<16 Wd, 16..18 Wf; k<16
        int j = i - OFF_W2DF, n = j / 32, k = j - n * 32;
        float v = 0.f;
        if (k < 16) { if (n < 16) v = W2d[k * 16 + n]; else if (n < 19) v = W2f[k * 3 + (n - 16)]; }
        ws[i] = f2b(v);
    } else if (i < OFF_W2UP) {                 // W2gT [16][128]
        int j = i - OFF_W2G, n = j / 128, k = j - n * 128;
        ws[i] = f2b(W2g[k * 16 + n]);
    } else if (i < WT_USH) {                   // W2upT [16][32], k<16 real
        int j = i - OFF_W2UP, n = j / 32, k = j - n * 32;
        ws[i] = (k < 16) ? f2b(W2up[k * 16 + n]) : (ushortT)0;
    }
}

// CSR-mode combined setup: weight transpose + degree histogram + bf16 node table.
// grid 625*256 = 160000 exactly. cur must be zeroed beforehand (memset).
__global__ __launch_bounds__(256) void setup_kernel(
    const float* __restrict__ W1so, const float* __restrict__ W2so,
    const float* __restrict__ W1d,  const float* __restrict__ W1f,
    const float* __restrict__ W1g,  const float* __restrict__ W1up,
    const float* __restrict__ W2d,  const float* __restrict__ W2f,
    const float* __restrict__ W2g,  const float* __restrict__ W2up,
    ushortT* __restrict__ ws,
    const void* __restrict__ eidx, int* __restrict__ cur,
    const float* __restrict__ node_s,
    ushortT* __restrict__ ns16)
{
    int i = blockIdx.x * 256 + threadIdx.x;
    // histogram
    {
        const int* pi = (const int*)eidx;
        const long long* pl = (const long long*)eidx;
        int r = idx_is64(pi) ? (int)pl[i] : pi[i];
        atomicAdd(&cur[r], 1);
    }
    // bf16 node_s table: 1,280,000 elems = 160,000 x 8
    if (ns16 && i < 160000) {
        float4 x = ((const float4*)node_s)[i * 2];
        float4 y = ((const float4*)node_s)[i * 2 + 1];
        uint4 st;
        st.x = pk2(x.x, x.y); st.y = pk2(x.z, x.w);
        st.z = pk2(y.x, y.y); st.w = pk2(y.z, y.w);
        ((uint4*)ns16)[i] = st;
    }
    // weight transpose (first 75,264 threads)
    weight_prep(i, W1so, W2so, W1d, W1f, W1g, W1up, W2d, W2f, W2g, W2up, ws);
}

// fallback (non-CSR): weight transpose + zero d_out
__global__ __launch_bounds__(256) void prep_kernel(
    const float* __restrict__ W1so, const float* __restrict__ W2so,
    const float* __restrict__ W1d,  const float* __restrict__ W1f,
    const float* __restrict__ W1g,  const float* __restrict__ W1up,
    const float* __restrict__ W2d,  const float* __restrict__ W2f,
    const float* __restrict__ W2g,  const float* __restrict__ W2up,
    ushortT* __restrict__ ws, float* __restrict__ out)
{
    int i = blockIdx.x * 256 + threadIdx.x;    // grid 294*256 = 75264
    float4* o4 = (float4*)out;
    #pragma unroll
    for (int k = 0; k < 6; ++k) {
        int z = i + k * 75264;
        if (z < 440000) o4[z] = make_float4(0.f, 0.f, 0.f, 0.f);
    }
    weight_prep(i, W1so, W2so, W1d, W1f, W1g, W1up, W2d, W2f, W2g, W2up, ws);
}

// single block: exclusive scan of cur[10000] -> noff[10001]; re-zero cur.
__global__ __launch_bounds__(256) void scan_kernel(int* __restrict__ cur,
                                                   int* __restrict__ noff)
{
    __shared__ int buf[10000];
    __shared__ int partial[256];
    const int t = threadIdx.x;
    for (int i = t; i < NN; i += 256) buf[i] = cur[i];
    for (int i = t; i < NN; i += 256) cur[i] = 0;
    __syncthreads();
    const int base = t * 40;
    int s = 0;
    #pragma unroll
    for (int i = 0; i < 40; ++i) s += (base + i < NN) ? buf[base + i] : 0;
    partial[t] = s;
    __syncthreads();
    for (int o = 1; o < 256; o <<= 1) {
        int v = (t >= o) ? partial[t - o] : 0;
        __syncthreads();
        partial[t] += v;
        __syncthreads();
    }
    int run = (t == 0) ? 0 : partial[t - 1];
    #pragma unroll
    for (int i = 0; i < 40; ++i) {
        int gi = base + i;
        if (gi < NN) { int v = buf[gi]; noff[gi] = run; run += v; }
    }
    if (t == 255) noff[NN] = partial[255];
}

#define MFMA(a, b, c) __builtin_amdgcn_mfma_f32_16x16x32_bf16((a), (b), (c), 0, 0, 0)

// Node-side precompute: Pr = node_s@W1so[0:128], Pc = node_s@W1so[160:288],
// both [10000][128] bf16. Blocks 0..624: 16 nodes x 128 cols each (MFMA).
// Block 625: the exclusive scan (folded to save a launch).
__global__ __launch_bounds__(256) void pre_kernel(
    const ushortT* __restrict__ ns16, const ushortT* __restrict__ wt,
    ushortT* __restrict__ prt, ushortT* __restrict__ pct,
    int* __restrict__ cur, int* __restrict__ noff)
{
    __shared__ int sbuf[10000];
    __shared__ int spart[256];
    const int t = threadIdx.x;
    if (blockIdx.x == 625) {     // ---- scan branch ----
        for (int i = t; i < NN; i += 256) sbuf[i] = cur[i];
        for (int i = t; i < NN; i += 256) cur[i] = 0;
        __syncthreads();
        const int base = t * 40;
        int s = 0;
        #pragma unroll
        for (int i = 0; i < 40; ++i) s += (base + i < NN) ? sbuf[base + i] : 0;
        spart[t] = s;
        __syncthreads();
        for (int o = 1; o < 256; o <<= 1) {
            int v = (t >= o) ? spart[t - o] : 0;
            __syncthreads();
            spart[t] += v;
            __syncthreads();
        }
        int run = (t == 0) ? 0 : spart[t - 1];
        #pragma unroll
        for (int i = 0; i < 40; ++i) {
            int gi = base + i;
            if (gi < NN) { int v = sbuf[gi]; noff[gi] = run; run += v; }
        }
        if (t == 255) noff[NN] = spart[255];
        return;
    }
    // ---- GEMM branch: 16 nodes x 128 cols ----
    const int w = t >> 6, lane = t & 63, lq = lane >> 4, ln = lane & 15, klq = lq * 8;
    const int nb = blockIdx.x * 16;
    const int dn0 = w * 32 + ln, dn1 = dn0 + 16;
    const ushortT* b0p = wt + dn0 * 352 + klq;
    const ushortT* b1p = wt + dn1 * 352 + klq;
    const ushortT* arow = ns16 + (size_t)(nb + ln) * 128 + klq;
    f32x4 a00 = {0,0,0,0}, a01 = {0,0,0,0}, a10 = {0,0,0,0}, a11 = {0,0,0,0};
    #pragma unroll
    for (int ks = 0; ks < 4; ++ks) {
        short8 a  = *(const short8*)(arow + ks * 32);
        short8 b0 = *(const short8*)(b0p + ks * 32);
        short8 b1 = *(const short8*)(b1p + ks * 32);
        short8 c0 = *(const short8*)(b0p + 160 + ks * 32);
        short8 c1 = *(const short8*)(b1p + 160 + ks * 32);
        a00 = MFMA(a, b0, a00); a01 = MFMA(a, b1, a01);
        a10 = MFMA(a, c0, a10); a11 = MFMA(a, c1, a11);
    }
    #pragma unroll
    for (int r = 0; r < 4; ++r) {
        int n = nb + lq * 4 + r;
        prt[(size_t)n * 128 + dn0] = f2b(a00[r]);
        prt[(size_t)n * 128 + dn1] = f2b(a01[r]);
        pct[(size_t)n * 128 + dn0] = f2b(a10[r]);
        pct[(size_t)n * 128 + dn1] = f2b(a11[r]);
    }
}

// one wave per node: FB rows are CSR-contiguous -> pure streaming read.
__global__ __launch_bounds__(256) void node_kernel(const ushortT* __restrict__ fb,
                                                   const int* __restrict__ noff,
                                                   float* __restrict__ out)
{
    const int w = threadIdx.x >> 6, l = threadIdx.x & 63;
    const int n = blockIdx.x * 4 + w;          // grid 2500 -> 10000 nodes
    if (l >= 44) return;                        // 44 lanes x 4 bf16 cols = 176
    const int s = noff[n], eend = noff[n + 1];
    float a0 = 0.f, a1 = 0.f, a2 = 0.f, a3 = 0.f;
    int idx = s;
    for (; idx + 2 <= eend; idx += 2) {
        uint2 p0 = *(const uint2*)(fb + (size_t)idx * 176 + l * 4);
        uint2 p1 = *(const uint2*)(fb + (size_t)(idx + 1) * 176 + l * 4);
        a0 += b2f((ushortT)(p0.x & 0xffff)); a1 += b2f((ushortT)(p0.x >> 16));
        a2 += b2f((ushortT)(p0.y & 0xffff)); a3 += b2f((ushortT)(p0.y >> 16));
        a0 += b2f((ushortT)(p1.x & 0xffff)); a1 += b2f((ushortT)(p1.x >> 16));
        a2 += b2f((ushortT)(p1.y & 0xffff)); a3 += b2f((ushortT)(p1.y >> 16));
    }
    if (idx < eend) {
        uint2 p0 = *(const uint2*)(fb + (size_t)idx * 176 + l * 4);
        a0 += b2f((ushortT)(p0.x & 0xffff)); a1 += b2f((ushortT)(p0.x >> 16));
        a2 += b2f((ushortT)(p0.y & 0xffff)); a3 += b2f((ushortT)(p0.y >> 16));
    }
    ((float4*)(out + (size_t)n * 176))[l] = make_float4(a0, a1, a2, a3);
}

// LDS 27,136 B. When prt/pct are present (pre mode), the per-edge node GEMM
// (ks0-3,5-8 of s_out1) is replaced by a gather of the precomputed Pr/Pc rows:
// loads issued in Phase A, summed into the dead mvA/m2 region during Phase C,
// added in-place at the D' epilogue. Per-wave: -32 MFMAs, -~26 scatter VMEMs.
__global__ __launch_bounds__(256, 6) void edge_kernel(
    const float* __restrict__ node_s, const float* __restrict__ node_v,
    const float* __restrict__ edge_s, const float* __restrict__ edge_v,
    const float* __restrict__ frames,
    const float* __restrict__ b1so, const float* __restrict__ b1g,
    const float* __restrict__ b2so, const float* __restrict__ b2g,
    const float* __restrict__ attW, const float* __restrict__ attb,
    const ushortT* __restrict__ wsc,
    const void* __restrict__ eidx, float* __restrict__ out,
    ushortT* __restrict__ fb, int* __restrict__ cur, const int* __restrict__ noff,
    const ushortT* __restrict__ ns16,
    const ushortT* __restrict__ prt, const ushortT* __restrict__ pct,
    int csr)
{
    const ushortT* W1T   = wsc + OFF_W1SO;
    const ushortT* W2T   = wsc + OFF_W2SO;
    const ushortT* W1dfT = wsc + OFF_W1DF;
    const ushortT* W1gT  = wsc + OFF_W1G;
    const ushortT* W1upT = wsc + OFF_W1UP;
    const ushortT* W2dfT = wsc + OFF_W2DF;
    const ushortT* W2gT  = wsc + OFF_W2G;
    const ushortT* W2upT = wsc + OFF_W2UP;

    __shared__ __align__(16) char smem[27136];
    ushortT* mvA     = (ushortT*)smem;                 // [96][40] (A->B) | m2 [32][168] (C->L)
    ushortT* m2      = (ushortT*)smem;
    ushortT* vhidA   = (ushortT*)(smem + 10752);       // [96][40] (B->E) | s2s [32][136] (I->L)
    ushortT* s2s     = (ushortT*)(smem + 10752);
    ushortT* normbuf = (ushortT*)(smem + 19456);       // [32][72] (A->D')
    ushortT* v1s     = (ushortT*)(smem + 19456);       // [96][16] E scratch (in-place -> vhid2A)
    ushortT* vhid2A  = (ushortT*)(smem + 19456);       // [96][16] (G->J)
    float*   fr      = (float*)(smem + 24064);         // [32][9]  (A->H)
    float*   vfr2f   = (float*)(smem + 25216);         // [96][3]  (G->H)
    ushortT* v1f     = (ushortT*)(smem + 24064);       // [96][16] (J->L, overlays fr/vfr2f)

    const int t  = threadIdx.x;
    const int eg = blockIdx.x * EPB;
    const int w  = t >> 6, lane = t & 63, lq = lane >> 4, ln = lane & 15;
    const int te = t >> 3, tj = t & 7;     // 8 threads per edge
    const int p  = w & 1;

    const int* pi = (const int*)eidx;
    const long long* pl = (const long long*)eidx;
    const bool is64 = idx_is64(pi);

    int posr = 0;          // CSR slot (tj==0 lanes); broadcast via __shfl in Phase L
    float att_reg = 0.f;   // attention gate

    const int nrT = is64 ? (int)pl[eg + te] : pi[eg + te];
    const int ncT = is64 ? (int)pl[E_TOT + eg + te] : pi[E_TOT + eg + te];

    // ==== Phase A: gathers (12-elem chunks: 3 float4 -> 6 packed uint) ====
    uint4 pga = {0,0,0,0}, pgb = {0,0,0,0}, pgc = {0,0,0,0}, pgd = {0,0,0,0};
    {
        #pragma unroll
        for (int mi = 0; mi < 2; ++mi) {
            if (mi == 1 && tj != 0) break;
            int m = (mi == 0) ? tj : 8;        // chunks 0..8; chunk = 4 c-cols x 3 sp
            const float* src;
            if (m < 4)       src = node_v + nrT * 48 + 12 * m;
            else if (m == 4) src = edge_v + (eg + te) * 12;
            else             src = node_v + ncT * 48 + 12 * (m - 5);
            float4 x = ((const float4*)src)[0];
            float4 y = ((const float4*)src)[1];
            float4 z = ((const float4*)src)[2];
            float v[12] = {x.x, x.y, x.z, x.w, y.x, y.y, y.z, y.w, z.x, z.y, z.z, z.w};
            int c0 = 4 * m;
            #pragma unroll
            for (int sp = 0; sp < 3; ++sp) {
                *(uintT*)(mvA + (sp * 32 + te) * 40 + c0)     = pk2(v[sp],     v[3 + sp]);
                *(uintT*)(mvA + (sp * 32 + te) * 40 + c0 + 2) = pk2(v[6 + sp], v[9 + sp]);
            }
        }
        // Pr/Pc row gather (pre mode): this thread's 16-col chunk of its edge's
        // precomputed node contributions. Held in registers until Phase C.
        if (prt) {
            const ushortT* pr_ = prt + (size_t)nrT * 128 + tj * 16;
            const ushortT* pc_ = pct + (size_t)ncT * 128 + tj * 16;
            pga = ((const uint4*)pr_)[0]; pgb = ((const uint4*)pr_)[1];
            pgc = ((const uint4*)pc_)[0]; pgd = ((const uint4*)pc_)[1];
        }
        #pragma unroll
        for (int k = 0; k < 2; ++k) {           // frames: 9 per edge
            int j = tj + k * 8;
            if (j < 9) fr[te * 9 + j] = frames[(eg + te) * 9 + j];
        }
        #pragma unroll
        for (int k = 0; k < 3; ++k) {           // normbuf cols 45..63 = 0
            int c = 45 + tj + k * 8;
            if (c < 64) normbuf[te * 72 + c] = 0;
        }
        if (t < 192) {                          // mvA cols 36..39 = 0
            int r = t >> 1, cc = 36 + ((t & 1) << 1);
            *(uintT*)(mvA + r * 40 + cc) = 0;
        }
        // CSR slot allocation: independent of all phases.
        if (csr && tj == 0) {
            posr = noff[nrT] + atomicAdd(&cur[nrT], 1);
        }
    }

    // ==== Phase A2 (pre-barrier): s_out1 global-K portion ====
    const int klq = lq * 8;
    const int dn0 = w * 32 + ln, dn1 = dn0 + 16;
    const ushortT* b0p = W1T + dn0 * 352 + klq;
    const ushortT* b1p = W1T + dn1 * 352 + klq;
    f32x4 acc00 = {0,0,0,0}, acc01 = {0,0,0,0}, acc10 = {0,0,0,0}, acc11 = {0,0,0,0};
    float dbi0, dbi1;
    {
        const int e0 = ln, e1 = 16 + ln;
        const int eb0 = (eg + e0) * 32, eb1 = (eg + e1) * 32;
        dbi0 = b1so[dn0]; dbi1 = b1so[dn1];
        if (prt) {
            // edge_s K-step only (k 128..159); node terms come from Pr/Pc gather.
            short8 a0 = ldfrag(edge_s + eb0 + klq);
            short8 a1 = ldfrag(edge_s + eb1 + klq);
            short8 b0 = *(const short8*)(b0p + 128);
            short8 b1 = *(const short8*)(b1p + 128);
            acc00 = MFMA(a0, b0, acc00); acc01 = MFMA(a0, b1, acc01);
            acc10 = MFMA(a1, b0, acc10); acc11 = MFMA(a1, b1, acc11);
        } else {
            int r0, c0, r1, c1;
            if (is64) {
                r0 = (int)pl[eg + e0]; r1 = (int)pl[eg + e1];
                c0 = (int)pl[E_TOT + eg + e0]; c1 = (int)pl[E_TOT + eg + e1];
            } else {
                r0 = pi[eg + e0]; r1 = pi[eg + e1];
                c0 = pi[E_TOT + eg + e0]; c1 = pi[E_TOT + eg + e1];
            }
            r0 *= 128; c0 *= 128; r1 *= 128; c1 *= 128;
            #pragma unroll
            for (int ks = 0; ks < 9; ++ks) {
                short8 a0, a1;
                if (ks < 4) {
                    if (ns16) {
                        a0 = *(const short8*)(ns16 + r0 + ks * 32 + klq);
                        a1 = *(const short8*)(ns16 + r1 + ks * 32 + klq);
                    } else {
                        a0 = ldfrag(node_s + r0 + ks * 32 + klq);
                        a1 = ldfrag(node_s + r1 + ks * 32 + klq);
                    }
                } else if (ks == 4) {
                    a0 = ldfrag(edge_s + eb0 + klq);
                    a1 = ldfrag(edge_s + eb1 + klq);
                } else {
                    if (ns16) {
                        a0 = *(const short8*)(ns16 + c0 + (ks - 5) * 32 + klq);
                        a1 = *(const short8*)(ns16 + c1 + (ks - 5) * 32 + klq);
                    } else {
                        a0 = ldfrag(node_s + c0 + (ks - 5) * 32 + klq);
                        a1 = ldfrag(node_s + c1 + (ks - 5) * 32 + klq);
                    }
                }
                short8 b0 = *(const short8*)(b0p + ks * 32);
                short8 b1 = *(const short8*)(b1p + ks * 32);
                acc00 = MFMA(a0, b0, acc00); acc01 = MFMA(a0, b1, acc01);
                acc10 = MFMA(a1, b0, acc10); acc11 = MFMA(a1, b1, acc11);
            }
        }
    }
    asm volatile("" : "+v"(acc00), "+v"(acc01), "+v"(acc10), "+v"(acc11));
    __syncthreads();   // (1)

    // ==== Phase B: mvA[96xK36] @ W1dfT[48][64] -> vhidA[96][<=40] ====
    for (int u = w; u < 18; u += 4) {
        int mt = u / 3, nt = u - mt * 3;
        const ushortT* ap = mvA + (mt * 16 + ln) * 40 + lq * 8;
        const ushortT* bp = W1dfT + (nt * 16 + ln) * 64 + lq * 8;
        f32x4 acc = {0.f, 0.f, 0.f, 0.f};
        acc = MFMA(*(const short8*)ap, *(const short8*)bp, acc);
        short8 a2 = {0, 0, 0, 0, 0, 0, 0, 0};
        if (lq == 0) a2 = *(const short8*)(ap + 32);
        acc = MFMA(a2, *(const short8*)(bp + 32), acc);
        if (nt < 2 || ln < 8) {
            ushortT* op = vhidA + (mt * 16 + lq * 4) * 40 + nt * 16 + ln;
            op[0]   = f2b(acc[0]); op[40]  = f2b(acc[1]);
            op[80]  = f2b(acc[2]); op[120] = f2b(acc[3]);
        }
    }
    __syncthreads();   // (2)

    // ==== Phase C: v_norm1 + local1 -> normbuf; Pr+Pc sum -> m2 cols 0..127 ====
    {
        #pragma unroll
        for (int k = 0; k < 5; ++k) {
            int h = tj + k * 8;
            if (h < 36) {
                float a0 = b2f(vhidA[te * 40 + h]);
                float a1 = b2f(vhidA[(32 + te) * 40 + h]);
                float a2 = b2f(vhidA[(64 + te) * 40 + h]);
                normbuf[te * 72 + h] = f2b(sqrtf(fmaf(a0, a0, fmaf(a1, a1, fmaf(a2, a2, 1e-8f)))));
            }
        }
        for (int i = t; i < 288; i += 256) {
            int e = i / 9, r = i - e * 9, a = r / 3, b = r - a * 3;
            float x = fr[e * 9 + b * 3 + 0] * b2f(vhidA[e * 40 + 36 + a])
                    + fr[e * 9 + b * 3 + 1] * b2f(vhidA[(32 + e) * 40 + 36 + a])
                    + fr[e * 9 + b * 3 + 2] * b2f(vhidA[(64 + e) * 40 + 36 + a]);
            normbuf[e * 72 + 36 + r] = f2b(x);
        }
        // Pr+Pc staged into the (dead) mvA region at m2 layout. Each slot is
        // written by exactly one thread here, consumed after barrier (3).
        if (prt) {
            uintT pr_[8] = {pga.x, pga.y, pga.z, pga.w, pgb.x, pgb.y, pgb.z, pgb.w};
            uintT pc_[8] = {pgc.x, pgc.y, pgc.z, pgc.w, pgd.x, pgd.y, pgd.z, pgd.w};
            uintT* dst = (uintT*)(m2 + te * 168 + tj * 16);
            #pragma unroll
            for (int j = 0; j < 8; ++j) {
                float lo = b2f((ushortT)(pr_[j] & 0xffff)) + b2f((ushortT)(pc_[j] & 0xffff));
                float hi = b2f((ushortT)(pr_[j] >> 16))    + b2f((ushortT)(pc_[j] >> 16));
                dst[j] = pk2(lo, hi);
            }
        }
    }
    __syncthreads();   // (3)

    // ==== Phase D': s_out1 normbuf K-steps (ks 9,10) + epilogue ====
    {
        const int e0 = ln, e1 = 16 + ln;
        #pragma unroll
        for (int ks = 9; ks < 11; ++ks) {
            short8 a0 = *(const short8*)(normbuf + e0 * 72 + (ks - 9) * 32 + klq);
            short8 a1 = *(const short8*)(normbuf + e1 * 72 + (ks - 9) * 32 + klq);
            short8 b0 = *(const short8*)(b0p + ks * 32);
            short8 b1 = *(const short8*)(b1p + ks * 32);
            acc00 = MFMA(a0, b0, acc00); acc01 = MFMA(a0, b1, acc01);
            acc10 = MFMA(a1, b0, acc10); acc11 = MFMA(a1, b1, acc11);
        }
        if (prt) {
            #pragma unroll
            for (int r = 0; r < 4; ++r) {
                int m0 = lq * 4 + r;
                float p00 = b2f(m2[m0 * 168 + dn0]);
                float p01 = b2f(m2[m0 * 168 + dn1]);
                float p10 = b2f(m2[(16 + m0) * 168 + dn0]);
                float p11 = b2f(m2[(16 + m0) * 168 + dn1]);
                m2[m0 * 168 + dn0]        = f2b(siluf_(acc00[r] + p00 + dbi0));
                m2[m0 * 168 + dn1]        = f2b(siluf_(acc01[r] + p01 + dbi1));
                m2[(16 + m0) * 168 + dn0] = f2b(siluf_(acc10[r] + p10 + dbi0));
                m2[(16 + m0) * 168 + dn1] = f2b(siluf_(acc11[r] + p11 + dbi1));
            }
        } else {
            #pragma unroll
            for (int r = 0; r < 4; ++r) {
                int m0 = lq * 4 + r;
                m2[m0 * 168 + dn0]        = f2b(siluf_(acc00[r] + dbi0));
                m2[m0 * 168 + dn1]        = f2b(siluf_(acc01[r] + dbi1));
                m2[(16 + m0) * 168 + dn0] = f2b(siluf_(acc10[r] + dbi0));
                m2[(16 + m0) * 168 + dn1] = f2b(siluf_(acc11[r] + dbi1));
            }
        }
    }
    __syncthreads();   // (4)

    // ==== Phase E+G (wave-local) ====
    float v1reg[2][4] = {{0.f,0.f,0.f,0.f},{0.f,0.f,0.f,0.f}};
    {
        f32x4 gacc = {0,0,0,0};
        {
            const ushortT* ap = m2 + (p * 16 + ln) * 168;
            const ushortT* bp = W1gT + ln * 128;
            #pragma unroll
            for (int ks = 0; ks < 4; ++ks)
                gacc = MFMA(*(const short8*)(ap + ks * 32 + lq * 8),
                            *(const short8*)(bp + ks * 32 + lq * 8), gacc);
        }
        float g1[4];
        {
            float bi = b1g[ln];
            #pragma unroll
            for (int r = 0; r < 4; ++r) g1[r] = sigmoidf_(gacc[r] + bi);
        }
        const ushortT* bpu = W1upT + ln * 64 + lq * 8;
        short8 bu1 = *(const short8*)bpu;
        short8 bu2 = *(const short8*)(bpu + 32);
        #pragma unroll
        for (int c = 0; c < 2; ++c) {
            if (c == 1 && w >= 2) break;
            int mt = w + c * 4;
            const ushortT* ap = vhidA + (mt * 16 + ln) * 40 + lq * 8;
            f32x4 acc = {0,0,0,0};
            acc = MFMA(*(const short8*)ap, bu1, acc);
            short8 a2 = {0, 0, 0, 0, 0, 0, 0, 0};
            if (lq == 0) a2 = *(const short8*)(ap + 32);
            acc = MFMA(a2, bu2, acc);
            #pragma unroll
            for (int r = 0; r < 4; ++r) {
                int row = mt * 16 + lq * 4 + r;
                float vv = acc[r] * g1[r];
                v1reg[c][r] = vv;
                v1s[row * 16 + ln] = f2b(vv);
            }
        }
        #pragma unroll
        for (int c = 0; c < 2; ++c) {
            if (c == 1 && w >= 2) break;
            int mt = w + c * 4;
            const ushortT* ap = v1s + (mt * 16 + ln) * 16 + lq * 8;
            short8 a = {0, 0, 0, 0, 0, 0, 0, 0};
            if (lq < 2) a = *(const short8*)ap;
            #pragma unroll
            for (int nt = 0; nt < 2; ++nt) {
                const ushortT* bp = W2dfT + (nt * 16 + ln) * 32 + lq * 8;
                f32x4 acc = {0,0,0,0};
                acc = MFMA(a, *(const short8*)bp, acc);
                if (nt == 0) {
                    ushortT* op = vhid2A + (mt * 16 + lq * 4) * 16 + ln;
                    op[0]  = f2b(acc[0]); op[16] = f2b(acc[1]);
                    op[32] = f2b(acc[2]); op[48] = f2b(acc[3]);
                } else if (ln < 3) {
                    float* op = vfr2f + (mt * 16 + lq * 4) * 3 + ln;
                    op[0] = acc[0]; op[3] = acc[1]; op[6] = acc[2]; op[9] = acc[3];
                }
            }
        }
    }
    __syncthreads();   // (5)

    // ==== Phase H: norm2 + local2 + zero pad into m2 cols 128..159 ====
    {
        #pragma unroll
        for (int k = 0; k < 2; ++k) {
            int i = t + k * 256, e = i >> 4, h = i & 15;
            float a0 = b2f(vhid2A[e * 16 + h]);
            float a1 = b2f(vhid2A[(32 + e) * 16 + h]);
            float a2 = b2f(vhid2A[(64 + e) * 16 + h]);
            m2[e * 168 + 128 + h] = f2b(sqrtf(fmaf(a0, a0, fmaf(a1, a1, fmaf(a2, a2, 1e-8f)))));
        }
        for (int i = t; i < 288; i += 256) {
            int e = i / 9, r = i - e * 9, a = r / 3, b = r - a * 3;
            float x = fr[e * 9 + b * 3 + 0] * vfr2f[e * 3 + a]
                    + fr[e * 9 + b * 3 + 1] * vfr2f[(32 + e) * 3 + a]
                    + fr[e * 9 + b * 3 + 2] * vfr2f[(64 + e) * 3 + a];
            m2[e * 168 + 144 + r] = f2b(x);
        }
        if (tj) m2[te * 168 + 152 + tj] = 0;
    }
    __syncthreads();   // (6)

    // ==== Phase I: s_out2 = m2[32][160] @ W2soT -> s2s (silu) ====
    {
        f32x4 acc00i = {0,0,0,0}, acc01i = {0,0,0,0}, acc10i = {0,0,0,0}, acc11i = {0,0,0,0};
        const ushortT* a0p = m2 + ln * 168 + lq * 8;
        const ushortT* a1p = m2 + (16 + ln) * 168 + lq * 8;
        const ushortT* b0pi = W2T + (w * 32 + ln) * 160 + lq * 8;
        const ushortT* b1pi = W2T + (w * 32 + 16 + ln) * 160 + lq * 8;
        #pragma unroll
        for (int ks = 0; ks < 5; ++ks) {
            short8 a0 = *(const short8*)(a0p + ks * 32);
            short8 a1 = *(const short8*)(a1p + ks * 32);
            short8 b0 = *(const short8*)(b0pi + ks * 32);
            short8 b1 = *(const short8*)(b1pi + ks * 32);
            acc00i = MFMA(a0, b0, acc00i); acc01i = MFMA(a0, b1, acc01i);
            acc10i = MFMA(a1, b0, acc10i); acc11i = MFMA(a1, b1, acc11i);
        }
        const int n0 = w * 32 + ln, n1 = n0 + 16;
        float bi0 = b2so[n0], bi1 = b2so[n1];
        #pragma unroll
        for (int r = 0; r < 4; ++r) {
            int m0 = lq * 4 + r;
            s2s[m0 * 136 + n0]        = f2b(siluf_(acc00i[r] + bi0));
            s2s[m0 * 136 + n1]        = f2b(siluf_(acc01i[r] + bi1));
            s2s[(16 + m0) * 136 + n0] = f2b(siluf_(acc10i[r] + bi0));
            s2s[(16 + m0) * 136 + n1] = f2b(siluf_(acc11i[r] + bi1));
        }
    }
    __syncthreads();   // (7)

    // ==== Phase J (wave-local) + attention ====
    {
        f32x4 gacc = {0,0,0,0};
        {
            const ushortT* ap = s2s + (p * 16 + ln) * 136;
            const ushortT* bp = W2gT + ln * 128;
            #pragma unroll
            for (int ks = 0; ks < 4; ++ks)
                gacc = MFMA(*(const short8*)(ap + ks * 32 + lq * 8),
                            *(const short8*)(bp + ks * 32 + lq * 8), gacc);
        }
        float g2[4];
        {
            float bi = b2g[ln];
            #pragma unroll
            for (int r = 0; r < 4; ++r) g2[r] = sigmoidf_(gacc[r] + bi);
        }
        const ushortT* bpu = W2upT + ln * 32 + lq * 8;
        short8 bu = *(const short8*)bpu;
        #pragma unroll
        for (int c = 0; c < 2; ++c) {
            if (c == 1 && w >= 2) break;
            int mt = w + c * 4;
            const ushortT* ap = vhid2A + (mt * 16 + ln) * 16 + lq * 8;
            short8 a = {0, 0, 0, 0, 0, 0, 0, 0};
            if (lq < 2) a = *(const short8*)ap;
            f32x4 acc = {0,0,0,0};
            acc = MFMA(a, bu, acc);
            #pragma unroll
            for (int r = 0; r < 4; ++r) {
                int row = mt * 16 + lq * 4 + r;
                float vfin = v1reg[c][r] + acc[r] * g2[r];
                v1f[row * 16 + ln] = f2b(vfin);
            }
        }
        {
            float sum = 0.f;
            int c0 = tj * 16;
            #pragma unroll
            for (int c = c0; c < c0 + 16; ++c)
                sum = fmaf(b2f(m2[te * 168 + c]) + b2f(s2s[te * 136 + c]), attW[c], sum);
            sum += __shfl_xor(sum, 4);
            sum += __shfl_xor(sum, 2);
            sum += __shfl_xor(sum, 1);
            att_reg = sigmoidf_(sum + attb[0]);
        }
    }
    __syncthreads();   // (8)

    // ==== Phase L: per-edge output ====
    {
        const float at = att_reg;
        if (csr) {
            const int pos = __shfl(posr, lane & 56);
            ushortT* fbe = fb + (size_t)pos * 176;
            #pragma unroll
            for (int k = 0; k < 11; ++k) {
                int j = 2 * tj + 16 * k;
                float v0, v1;
                if (j < 128) {
                    v0 = (b2f(m2[te * 168 + j])     + b2f(s2s[te * 136 + j]))     * at;
                    v1 = (b2f(m2[te * 168 + j + 1]) + b2f(s2s[te * 136 + j + 1])) * at;
                } else {
                    int r = j - 128;
                    int o0 = r / 3,        sp0 = r - o0 * 3;
                    int o1 = (r + 1) / 3,  sp1 = (r + 1) - o1 * 3;
                    v0 = b2f(v1f[(sp0 * 32 + te) * 16 + o0]);
                    v1 = b2f(v1f[(sp1 * 32 + te) * 16 + o1]);
                }
                *(uintT*)(fbe + j) = pk2(v0, v1);
            }
        } else {
            const int orow = nrT * 176;
            #pragma unroll
            for (int k = 0; k < 22; ++k) {
                int j = tj + k * 8;
                float val;
                if (j < 128) {
                    val = (b2f(m2[te * 168 + j]) + b2f(s2s[te * 136 + j])) * at;
                } else {
                    int r = j - 128, o = r / 3, sp = r - o * 3;
                    val = b2f(v1f[(sp * 32 + te) * 16 + o]);
                }
                atomicAdd(&out[orow + j], val);
            }
        }
    }
}

extern "C" void kernel_launch(void* const* d_in, const int* in_sizes, int n_in,
                              void* d_out, int out_size, void* d_ws, size_t ws_size,
                              hipStream_t stream) {
    const float* node_s = (const float*)d_in[0];
    const float* node_v = (const float*)d_in[1];
    const float* edge_s = (const float*)d_in[2];
    const float* edge_v = (const float*)d_in[3];
    const float* frames = (const float*)d_in[4];
    const float* W1d  = (const float*)d_in[5];
    const float* W1f  = (const float*)d_in[6];
    const float* W1so = (const float*)d_in[7];
    const float* b1so = (const float*)d_in[8];
    const float* W1up = (const float*)d_in[9];
    const float* W1g  = (const float*)d_in[10];
    const float* b1g  = (const float*)d_in[11];
    const float* W2d  = (const float*)d_in[12];
    const float* W2f  = (const float*)d_in[13];
    const float* W2so = (const float*)d_in[14];
    const float* b2so = (const float*)d_in[15];
    const float* W2up = (const float*)d_in[16];
    const float* W2g  = (const float*)d_in[17];
    const float* b2g  = (const float*)d_in[18];
    const float* attW = (const float*)d_in[19];
    const float* attb = (const float*)d_in[20];
    const void*  eidx = d_in[21];

    float* out = (float*)d_out;
    char* ws = (char*)d_ws;

    const int csr = ws_size >= WS_CSR;
    ushortT* wt    = csr ? (ushortT*)(ws + WT_OFF)  : (ushortT*)ws;
    ushortT* fbuf  = csr ? (ushortT*)ws             : nullptr;
    int*     noff  = csr ? (int*)(ws + NOFF_OFF)    : nullptr;
    int*     cur   = csr ? (int*)(ws + CUR_OFF)     : nullptr;
    ushortT* ns16  = (ws_size >= WS_NS) ? (ushortT*)(ws + NS16_OFF) : nullptr;
    const int pre  = csr && ns16 && (ws_size >= PRE_END);
    ushortT* prt   = pre ? (ushortT*)(ws + PR_OFF) : nullptr;
    ushortT* pct   = pre ? (ushortT*)(ws + PC_OFF) : nullptr;

    if (csr) {
        hipMemsetAsync(cur, 0, NN * sizeof(int), stream);
        setup_kernel<<<625, 256, 0, stream>>>(
            W1so, W2so, W1d, W1f, W1g, W1up, W2d, W2f, W2g, W2up,
            wt, eidx, cur, node_s, ns16);
        if (pre) {
            pre_kernel<<<626, 256, 0, stream>>>(ns16, wt, prt, pct, cur, noff);
        } else {
            scan_kernel<<<1, 256, 0, stream>>>(cur, noff);
        }
    } else {
        prep_kernel<<<294, 256, 0, stream>>>(W1so, W2so, W1d, W1f, W1g, W1up,
                                             W2d, W2f, W2g, W2up, wt, out);
    }

    edge_kernel<<<E_TOT / EPB, 256, 0, stream>>>(
        node_s, node_v, edge_s, edge_v, frames,
        b1so, b1g, b2so, b2g, attW, attb,
        (const ushortT*)wt, eidx, out, fbuf, cur, noff, ns16, prt, pct, csr);

    if (csr) {
        node_kernel<<<2500, 256, 0, stream>>>((const ushortT*)fbuf, noff, out);
    }
}

// Round 5
// 271.690 us; speedup vs baseline: 1.1509x; 1.0226x over previous
//
#include <hip/hip_runtime.h>
#include <hip/hip_bf16.h>

#define E_TOT 160000
#define NN    10000
#define EPB   32      // edges per block

typedef unsigned short ushortT;
typedef unsigned int   uintT;
typedef __attribute__((ext_vector_type(8))) short short8;
typedef __attribute__((ext_vector_type(4))) float f32x4;

__device__ __forceinline__ float sigmoidf_(float x) { return 1.0f / (1.0f + __expf(-x)); }
__device__ __forceinline__ float siluf_(float x) { return x * sigmoidf_(x); }

__device__ __forceinline__ ushortT f2b(float f) {
    union { float f; uintT u; } x; x.f = f;
    uintT r = x.u + 0x7fffu + ((x.u >> 16) & 1u);
    return (ushortT)(r >> 16);
}
__device__ __forceinline__ float b2f(ushortT h) {
    union { uintT u; float f; } x; x.u = ((uintT)h) << 16; return x.f;
}
__device__ __forceinline__ uintT pk2(float lo, float hi) {
    union { __hip_bfloat162 h; uintT u; } cv;
    cv.h = __float22bfloat162_rn(make_float2(lo, hi));
    return cv.u;
}
// 8 consecutive fp32 -> bf16 MFMA A-fragment
__device__ __forceinline__ short8 ldfrag(const float* p) {
    const float4 x = ((const float4*)p)[0];
    const float4 y = ((const float4*)p)[1];
    union { uintT u[4]; short8 s; } r;
    r.u[0] = pk2(x.x, x.y); r.u[1] = pk2(x.z, x.w);
    r.u[2] = pk2(y.x, y.y); r.u[3] = pk2(y.z, y.w);
    return r.s;
}

// ---- weight-table layout (ushort offsets within wt) ----
#define OFF_W1SO 0
#define OFF_W2SO 45056
#define OFF_W1DF 65536
#define OFF_W1G  68608
#define OFF_W1UP 70656
#define OFF_W2DF 71680
#define OFF_W2G  72704
#define OFF_W2UP 74752
#define WT_USH   75264

// ---- CSR workspace layout (bytes from ws base) ----
#define NOFF_OFF   56320000ULL
#define CUR_OFF    56360016ULL
#define WT_OFF     57040032ULL
#define WS_CSR     57190560ULL
#define PR_OFF     57190560ULL              // bf16 Pr = node_s@W1so[0:128]   [10000][128]
#define PC_OFF     59750560ULL              // bf16 Pc = node_s@W1so[160:288] [10000][128]
#define PRE_END    62310560ULL

__device__ __forceinline__ bool idx_is64(const int* pi) {
    return (pi[1] | pi[3] | pi[5] | pi[7] | pi[9] | pi[11] | pi[13] | pi[15]) == 0;
}

// weight transpose helper (shared by setup_kernel and fallback prep_kernel)
__device__ __forceinline__ void weight_prep(
    int i,
    const float* __restrict__ W1so, const float* __restrict__ W2so,
    const float* __restrict__ W1d,  const float* __restrict__ W1f,
    const float* __restrict__ W1g,  const float* __restrict__ W1up,
    const float* __restrict__ W2d,  const float* __restrict__ W2f,
    const float* __restrict__ W2g,  const float* __restrict__ W2up,
    ushortT* __restrict__ ws)
{
    if (i < OFF_W2SO) {                        // W1soT [n=128][k=352], k<333 real
        int n = i / 352, k = i - n * 352;
        ws[i] = (k < 333) ? f2b(W1so[k * 128 + n]) : (ushortT)0;
    } else if (i < OFF_W1DF) {                 // W2soT [128][160], k<153 real
        int j = i - OFF_W2SO, n = j / 160, k = j - n * 160;
        ws[i] = (k < 153) ? f2b(W2so[k * 128 + n]) : (ushortT)0;
    } else if (i < OFF_W1G) {                  // W1dfT [48][64]: n<36 Wd, 36..38 Wf
        int j = i - OFF_W1DF, n = j / 64, k = j - n * 64;
        float v = 0.f;
        if (k < 36) { if (n < 36) v = W1d[k * 36 + n]; else if (n < 39) v = W1f[k * 3 + (n - 36)]; }
        ws[i] = f2b(v);
    } else if (i < OFF_W1UP) {                 // W1gT [16][128]
        int j = i - OFF_W1G, n = j / 128, k = j - n * 128;
        ws[i] = f2b(W1g[k * 16 + n]);
    } else if (i < OFF_W2DF) {                 // W1upT [16][64], k<36 real
        int j = i - OFF_W1UP, n = j / 64, k = j - n * 64;
        ws[i] = (k < 36) ? f2b(W1up[k * 16 + n]) : (ushortT)0;
    } else if (i < OFF_W2G) {                  // W2dfT [32][32]: n<16 Wd, 16..18 Wf; k<16
        int j = i - OFF_W2DF, n = j / 32, k = j - n * 32;
        float v = 0.f;
        if (k < 16) { if (n < 16) v = W2d[k * 16 + n]; else if (n < 19) v = W2f[k * 3 + (n - 16)]; }
        ws[i] = f2b(v);
    } else if (i < OFF_W2UP) {                 // W2gT [16][128]
        int j = i - OFF_W2G, n = j / 128, k = j - n * 128;
        ws[i] = f2b(W2g[k * 16 + n]);
    } else if (i < WT_USH) {                   // W2upT [16][32], k<16 real
        int j = i - OFF_W2UP, n = j / 32, k = j - n * 32;
        ws[i] = (k < 16) ? f2b(W2up[k * 16 + n]) : (ushortT)0;
    }
}

#define MFMA(a, b, c) __builtin_amdgcn_mfma_f32_16x16x32_bf16((a), (b), (c), 0, 0, 0)

// Fused setup: blocks 0..624 do weight transpose + degree histogram;
// blocks 625..781 compute Pr = node_s@W1so[0:128] and Pc = node_s@W1so[160:288]
// ([10000][128] bf16 each) from fp32 inputs directly. Each GEMM block builds a
// bf16 transpose of the needed W1so rows in a 32 KB LDS tile, TWO PASSES
// (rows 0..127 -> Pr, then rows 160..287 -> Pc) so the static LDS stays at
// 32 KB (the 64 KB single-pass variant was at the static-shared limit).
// No dependency on the wt table -> runs concurrently with the setup blocks.
// cur must be zeroed beforehand (memset).
__global__ __launch_bounds__(256) void setup_kernel(
    const float* __restrict__ W1so, const float* __restrict__ W2so,
    const float* __restrict__ W1d,  const float* __restrict__ W1f,
    const float* __restrict__ W1g,  const float* __restrict__ W1up,
    const float* __restrict__ W2d,  const float* __restrict__ W2f,
    const float* __restrict__ W2g,  const float* __restrict__ W2up,
    ushortT* __restrict__ ws,
    const void* __restrict__ eidx, int* __restrict__ cur,
    const float* __restrict__ node_s,
    ushortT* __restrict__ prt, ushortT* __restrict__ pct)
{
    __shared__ __align__(16) ushortT wtile[128 * 128];   // 32 KB (GEMM branch only)
    const int t = threadIdx.x;

    if (blockIdx.x >= 625) {
        // ---- Pr/Pc GEMM branch: 64 nodes per block, 2 passes ----
        if (!prt) return;
        const int nb = (blockIdx.x - 625) * 64;
        const int w = t >> 6, lane = t & 63, lq = lane >> 4, ln = lane & 15, klq = lq * 8;
        int arow = nb + w * 16 + ln;
        if (arow > NN - 1) arow = NN - 1;                 // clamp OOB loads (stores guarded)
        short8 af[4];
        #pragma unroll
        for (int ks = 0; ks < 4; ++ks)
            af[ks] = ldfrag(node_s + (size_t)arow * 128 + ks * 32 + klq);
        const int n_ = t & 127, half = t >> 7, nsw8 = n_ & 7;
        for (int pass = 0; pass < 2; ++pass) {
            // Transpose W1so rows base..base+127 -> wtile[n][k] bf16.
            // Swizzle: 16B block index k8 -> k8 ^ (n&7) (keeps 16B frags intact).
            const int base = pass ? 160 : 0;
            for (int kk = 0; kk < 64; ++kk) {
                int kt = kk * 2 + half;                   // 0..127
                float v = W1so[(base + kt) * 128 + n_];
                wtile[n_ * 128 + ((((kt >> 3) ^ nsw8) << 3) | (kt & 7))] = f2b(v);
            }
            __syncthreads();
            ushortT* dst = pass ? pct : prt;
            #pragma unroll
            for (int ct = 0; ct < 8; ++ct) {
                f32x4 ar = {0, 0, 0, 0};
                const int n = ct * 16 + ln, nsw = n & 7;
                #pragma unroll
                for (int ks = 0; ks < 4; ++ks) {
                    const int kb = ks * 32 + klq;
                    const short8 br = *(const short8*)(wtile + n * 128 + (((kb >> 3) ^ nsw) << 3));
                    ar = MFMA(af[ks], br, ar);
                }
                #pragma unroll
                for (int r = 0; r < 4; ++r) {
                    const int node = nb + w * 16 + lq * 4 + r;
                    if (node < NN) dst[(size_t)node * 128 + ct * 16 + ln] = f2b(ar[r]);
                }
            }
            __syncthreads();   // all reads done before pass-1 overwrites wtile
        }
        return;
    }

    // ---- setup branch ----
    int i = blockIdx.x * 256 + t;
    {
        const int* pi = (const int*)eidx;
        const long long* pl = (const long long*)eidx;
        int r = idx_is64(pi) ? (int)pl[i] : pi[i];
        atomicAdd(&cur[r], 1);
    }
    weight_prep(i, W1so, W2so, W1d, W1f, W1g, W1up, W2d, W2f, W2g, W2up, ws);
}

// fallback (non-CSR): weight transpose + zero d_out
__global__ __launch_bounds__(256) void prep_kernel(
    const float* __restrict__ W1so, const float* __restrict__ W2so,
    const float* __restrict__ W1d,  const float* __restrict__ W1f,
    const float* __restrict__ W1g,  const float* __restrict__ W1up,
    const float* __restrict__ W2d,  const float* __restrict__ W2f,
    const float* __restrict__ W2g,  const float* __restrict__ W2up,
    ushortT* __restrict__ ws, float* __restrict__ out)
{
    int i = blockIdx.x * 256 + threadIdx.x;    // grid 294*256 = 75264
    float4* o4 = (float4*)out;
    #pragma unroll
    for (int k = 0; k < 6; ++k) {
        int z = i + k * 75264;
        if (z < 440000) o4[z] = make_float4(0.f, 0.f, 0.f, 0.f);
    }
    weight_prep(i, W1so, W2so, W1d, W1f, W1g, W1up, W2d, W2f, W2g, W2up, ws);
}

// single block: exclusive scan of cur[10000] -> noff[10001]; re-zero cur.
__global__ __launch_bounds__(256) void scan_kernel(int* __restrict__ cur,
                                                   int* __restrict__ noff)
{
    __shared__ int buf[10000];
    __shared__ int partial[256];
    const int t = threadIdx.x;
    for (int i = t; i < NN; i += 256) buf[i] = cur[i];
    for (int i = t; i < NN; i += 256) cur[i] = 0;
    __syncthreads();
    const int base = t * 40;
    int s = 0;
    #pragma unroll
    for (int i = 0; i < 40; ++i) s += (base + i < NN) ? buf[base + i] : 0;
    partial[t] = s;
    __syncthreads();
    for (int o = 1; o < 256; o <<= 1) {
        int v = (t >= o) ? partial[t - o] : 0;
        __syncthreads();
        partial[t] += v;
        __syncthreads();
    }
    int run = (t == 0) ? 0 : partial[t - 1];
    #pragma unroll
    for (int i = 0; i < 40; ++i) {
        int gi = base + i;
        if (gi < NN) { int v = buf[gi]; noff[gi] = run; run += v; }
    }
    if (t == 255) noff[NN] = partial[255];
}

// one wave per node: FB rows are CSR-contiguous -> pure streaming read.
// Unroll 4 -> 4 row-loads in flight per wave (latency hiding).
__global__ __launch_bounds__(256) void node_kernel(const ushortT* __restrict__ fb,
                                                   const int* __restrict__ noff,
                                                   float* __restrict__ out)
{
    const int w = threadIdx.x >> 6, l = threadIdx.x & 63;
    const int n = blockIdx.x * 4 + w;          // grid 2500 -> 10000 nodes
    if (l >= 44) return;                        // 44 lanes x 4 bf16 cols = 176
    const int s = noff[n], eend = noff[n + 1];
    float a0 = 0.f, a1 = 0.f, a2 = 0.f, a3 = 0.f;
    int idx = s;
    for (; idx + 4 <= eend; idx += 4) {
        uint2 p0 = *(const uint2*)(fb + (size_t)idx * 176 + l * 4);
        uint2 p1 = *(const uint2*)(fb + (size_t)(idx + 1) * 176 + l * 4);
        uint2 p2 = *(const uint2*)(fb + (size_t)(idx + 2) * 176 + l * 4);
        uint2 p3 = *(const uint2*)(fb + (size_t)(idx + 3) * 176 + l * 4);
        a0 += b2f((ushortT)(p0.x & 0xffff)); a1 += b2f((ushortT)(p0.x >> 16));
        a2 += b2f((ushortT)(p0.y & 0xffff)); a3 += b2f((ushortT)(p0.y >> 16));
        a0 += b2f((ushortT)(p1.x & 0xffff)); a1 += b2f((ushortT)(p1.x >> 16));
        a2 += b2f((ushortT)(p1.y & 0xffff)); a3 += b2f((ushortT)(p1.y >> 16));
        a0 += b2f((ushortT)(p2.x & 0xffff)); a1 += b2f((ushortT)(p2.x >> 16));
        a2 += b2f((ushortT)(p2.y & 0xffff)); a3 += b2f((ushortT)(p2.y >> 16));
        a0 += b2f((ushortT)(p3.x & 0xffff)); a1 += b2f((ushortT)(p3.x >> 16));
        a2 += b2f((ushortT)(p3.y & 0xffff)); a3 += b2f((ushortT)(p3.y >> 16));
    }
    for (; idx < eend; ++idx) {
        uint2 p0 = *(const uint2*)(fb + (size_t)idx * 176 + l * 4);
        a0 += b2f((ushortT)(p0.x & 0xffff)); a1 += b2f((ushortT)(p0.x >> 16));
        a2 += b2f((ushortT)(p0.y & 0xffff)); a3 += b2f((ushortT)(p0.y >> 16));
    }
    ((float4*)(out + (size_t)n * 176))[l] = make_float4(a0, a1, a2, a3);
}

// LDS 27,136 B. When prt/pct are present (pre mode), the per-edge node GEMM
// (ks0-3,5-8 of s_out1) is replaced by a gather of the precomputed Pr/Pc rows:
// loads issued in Phase A, summed into the dead mvA/m2 region during Phase C,
// added in-place at the D' epilogue. Per-wave: -32 MFMAs, -~26 scatter VMEMs.
__global__ __launch_bounds__(256, 6) void edge_kernel(
    const float* __restrict__ node_s, const float* __restrict__ node_v,
    const float* __restrict__ edge_s, const float* __restrict__ edge_v,
    const float* __restrict__ frames,
    const float* __restrict__ b1so, const float* __restrict__ b1g,
    const float* __restrict__ b2so, const float* __restrict__ b2g,
    const float* __restrict__ attW, const float* __restrict__ attb,
    const ushortT* __restrict__ wsc,
    const void* __restrict__ eidx, float* __restrict__ out,
    ushortT* __restrict__ fb, int* __restrict__ cur, const int* __restrict__ noff,
    const ushortT* __restrict__ ns16,
    const ushortT* __restrict__ prt, const ushortT* __restrict__ pct,
    int csr)
{
    const ushortT* W1T   = wsc + OFF_W1SO;
    const ushortT* W2T   = wsc + OFF_W2SO;
    const ushortT* W1dfT = wsc + OFF_W1DF;
    const ushortT* W1gT  = wsc + OFF_W1G;
    const ushortT* W1upT = wsc + OFF_W1UP;
    const ushortT* W2dfT = wsc + OFF_W2DF;
    const ushortT* W2gT  = wsc + OFF_W2G;
    const ushortT* W2upT = wsc + OFF_W2UP;

    __shared__ __align__(16) char smem[27136];
    ushortT* mvA     = (ushortT*)smem;                 // [96][40] (A->B) | m2 [32][168] (C->L)
    ushortT* m2      = (ushortT*)smem;
    ushortT* vhidA   = (ushortT*)(smem + 10752);       // [96][40] (B->E) | s2s [32][136] (I->L)
    ushortT* s2s     = (ushortT*)(smem + 10752);
    ushortT* normbuf = (ushortT*)(smem + 19456);       // [32][72] (A->D')
    ushortT* v1s     = (ushortT*)(smem + 19456);       // [96][16] E scratch (in-place -> vhid2A)
    ushortT* vhid2A  = (ushortT*)(smem + 19456);       // [96][16] (G->J)
    float*   fr      = (float*)(smem + 24064);         // [32][9]  (A->H)
    float*   vfr2f   = (float*)(smem + 25216);         // [96][3]  (G->H)
    ushortT* v1f     = (ushortT*)(smem + 24064);       // [96][16] (J->L, overlays fr/vfr2f)

    const int t  = threadIdx.x;
    const int eg = blockIdx.x * EPB;
    const int w  = t >> 6, lane = t & 63, lq = lane >> 4, ln = lane & 15;
    const int te = t >> 3, tj = t & 7;     // 8 threads per edge
    const int p  = w & 1;

    const int* pi = (const int*)eidx;
    const long long* pl = (const long long*)eidx;
    const bool is64 = idx_is64(pi);

    int posr = 0;          // CSR slot (tj==0 lanes); broadcast via __shfl in Phase L
    float att_reg = 0.f;   // attention gate

    const int nrT = is64 ? (int)pl[eg + te] : pi[eg + te];
    const int ncT = is64 ? (int)pl[E_TOT + eg + te] : pi[E_TOT + eg + te];

    // ==== Phase A: gathers (12-elem chunks: 3 float4 -> 6 packed uint) ====
    uint4 pga = {0,0,0,0}, pgb = {0,0,0,0}, pgc = {0,0,0,0}, pgd = {0,0,0,0};
    {
        #pragma unroll
        for (int mi = 0; mi < 2; ++mi) {
            if (mi == 1 && tj != 0) break;
            int m = (mi == 0) ? tj : 8;        // chunks 0..8; chunk = 4 c-cols x 3 sp
            const float* src;
            if (m < 4)       src = node_v + nrT * 48 + 12 * m;
            else if (m == 4) src = edge_v + (eg + te) * 12;
            else             src = node_v + ncT * 48 + 12 * (m - 5);
            float4 x = ((const float4*)src)[0];
            float4 y = ((const float4*)src)[1];
            float4 z = ((const float4*)src)[2];
            float v[12] = {x.x, x.y, x.z, x.w, y.x, y.y, y.z, y.w, z.x, z.y, z.z, z.w};
            int c0 = 4 * m;
            #pragma unroll
            for (int sp = 0; sp < 3; ++sp) {
                *(uintT*)(mvA + (sp * 32 + te) * 40 + c0)     = pk2(v[sp],     v[3 + sp]);
                *(uintT*)(mvA + (sp * 32 + te) * 40 + c0 + 2) = pk2(v[6 + sp], v[9 + sp]);
            }
        }
        // Pr/Pc row gather (pre mode): this thread's 16-col chunk of its edge's
        // precomputed node contributions. Held in registers until Phase C.
        if (prt) {
            const ushortT* pr_ = prt + (size_t)nrT * 128 + tj * 16;
            const ushortT* pc_ = pct + (size_t)ncT * 128 + tj * 16;
            pga = ((const uint4*)pr_)[0]; pgb = ((const uint4*)pr_)[1];
            pgc = ((const uint4*)pc_)[0]; pgd = ((const uint4*)pc_)[1];
        }
        #pragma unroll
        for (int k = 0; k < 2; ++k) {           // frames: 9 per edge
            int j = tj + k * 8;
            if (j < 9) fr[te * 9 + j] = frames[(eg + te) * 9 + j];
        }
        #pragma unroll
        for (int k = 0; k < 3; ++k) {           // normbuf cols 45..63 = 0
            int c = 45 + tj + k * 8;
            if (c < 64) normbuf[te * 72 + c] = 0;
        }
        if (t < 192) {                          // mvA cols 36..39 = 0
            int r = t >> 1, cc = 36 + ((t & 1) << 1);
            *(uintT*)(mvA + r * 40 + cc) = 0;
        }
        // CSR slot allocation: independent of all phases.
        if (csr && tj == 0) {
            posr = noff[nrT] + atomicAdd(&cur[nrT], 1);
        }
    }

    // ==== Phase A2 (pre-barrier): s_out1 global-K portion ====
    const int klq = lq * 8;
    const int dn0 = w * 32 + ln, dn1 = dn0 + 16;
    const ushortT* b0p = W1T + dn0 * 352 + klq;
    const ushortT* b1p = W1T + dn1 * 352 + klq;
    f32x4 acc00 = {0,0,0,0}, acc01 = {0,0,0,0}, acc10 = {0,0,0,0}, acc11 = {0,0,0,0};
    float dbi0, dbi1;
    {
        const int e0 = ln, e1 = 16 + ln;
        const int eb0 = (eg + e0) * 32, eb1 = (eg + e1) * 32;
        dbi0 = b1so[dn0]; dbi1 = b1so[dn1];
        if (prt) {
            // edge_s K-step only (k 128..159); node terms come from Pr/Pc gather.
            short8 a0 = ldfrag(edge_s + eb0 + klq);
            short8 a1 = ldfrag(edge_s + eb1 + klq);
            short8 b0 = *(const short8*)(b0p + 128);
            short8 b1 = *(const short8*)(b1p + 128);
            acc00 = MFMA(a0, b0, acc00); acc01 = MFMA(a0, b1, acc01);
            acc10 = MFMA(a1, b0, acc10); acc11 = MFMA(a1, b1, acc11);
        } else {
            int r0, c0, r1, c1;
            if (is64) {
                r0 = (int)pl[eg + e0]; r1 = (int)pl[eg + e1];
                c0 = (int)pl[E_TOT + eg + e0]; c1 = (int)pl[E_TOT + eg + e1];
            } else {
                r0 = pi[eg + e0]; r1 = pi[eg + e1];
                c0 = pi[E_TOT + eg + e0]; c1 = pi[E_TOT + eg + e1];
            }
            r0 *= 128; c0 *= 128; r1 *= 128; c1 *= 128;
            #pragma unroll
            for (int ks = 0; ks < 9; ++ks) {
                short8 a0, a1;
                if (ks < 4) {
                    a0 = ldfrag(node_s + r0 + ks * 32 + klq);
                    a1 = ldfrag(node_s + r1 + ks * 32 + klq);
                } else if (ks == 4) {
                    a0 = ldfrag(edge_s + eb0 + klq);
                    a1 = ldfrag(edge_s + eb1 + klq);
                } else {
                    a0 = ldfrag(node_s + c0 + (ks - 5) * 32 + klq);
                    a1 = ldfrag(node_s + c1 + (ks - 5) * 32 + klq);
                }
                short8 b0 = *(const short8*)(b0p + ks * 32);
                short8 b1 = *(const short8*)(b1p + ks * 32);
                acc00 = MFMA(a0, b0, acc00); acc01 = MFMA(a0, b1, acc01);
                acc10 = MFMA(a1, b0, acc10); acc11 = MFMA(a1, b1, acc11);
            }
        }
    }
    asm volatile("" : "+v"(acc00), "+v"(acc01), "+v"(acc10), "+v"(acc11));
    __syncthreads();   // (1)

    // ==== Phase B: mvA[96xK36] @ W1dfT[48][64] -> vhidA[96][<=40] ====
    for (int u = w; u < 18; u += 4) {
        int mt = u / 3, nt = u - mt * 3;
        const ushortT* ap = mvA + (mt * 16 + ln) * 40 + lq * 8;
        const ushortT* bp = W1dfT + (nt * 16 + ln) * 64 + lq * 8;
        f32x4 acc = {0.f, 0.f, 0.f, 0.f};
        acc = MFMA(*(const short8*)ap, *(const short8*)bp, acc);
        short8 a2 = {0, 0, 0, 0, 0, 0, 0, 0};
        if (lq == 0) a2 = *(const short8*)(ap + 32);
        acc = MFMA(a2, *(const short8*)(bp + 32), acc);
        if (nt < 2 || ln < 8) {
            ushortT* op = vhidA + (mt * 16 + lq * 4) * 40 + nt * 16 + ln;
            op[0]   = f2b(acc[0]); op[40]  = f2b(acc[1]);
            op[80]  = f2b(acc[2]); op[120] = f2b(acc[3]);
        }
    }
    __syncthreads();   // (2)

    // ==== Phase C: v_norm1 + local1 -> normbuf; Pr+Pc sum -> m2 cols 0..127 ====
    {
        #pragma unroll
        for (int k = 0; k < 5; ++k) {
            int h = tj + k * 8;
            if (h < 36) {
                float a0 = b2f(vhidA[te * 40 + h]);
                float a1 = b2f(vhidA[(32 + te) * 40 + h]);
                float a2 = b2f(vhidA[(64 + te) * 40 + h]);
                normbuf[te * 72 + h] = f2b(sqrtf(fmaf(a0, a0, fmaf(a1, a1, fmaf(a2, a2, 1e-8f)))));
            }
        }
        for (int i = t; i < 288; i += 256) {
            int e = i / 9, r = i - e * 9, a = r / 3, b = r - a * 3;
            float x = fr[e * 9 + b * 3 + 0] * b2f(vhidA[e * 40 + 36 + a])
                    + fr[e * 9 + b * 3 + 1] * b2f(vhidA[(32 + e) * 40 + 36 + a])
                    + fr[e * 9 + b * 3 + 2] * b2f(vhidA[(64 + e) * 40 + 36 + a]);
            normbuf[e * 72 + 36 + r] = f2b(x);
        }
        // Pr+Pc staged into the (dead) mvA region at m2 layout.
        if (prt) {
            uintT pr_[8] = {pga.x, pga.y, pga.z, pga.w, pgb.x, pgb.y, pgb.z, pgb.w};
            uintT pc_[8] = {pgc.x, pgc.y, pgc.z, pgc.w, pgd.x, pgd.y, pgd.z, pgd.w};
            uintT* dst = (uintT*)(m2 + te * 168 + tj * 16);
            #pragma unroll
            for (int j = 0; j < 8; ++j) {
                float lo = b2f((ushortT)(pr_[j] & 0xffff)) + b2f((ushortT)(pc_[j] & 0xffff));
                float hi = b2f((ushortT)(pr_[j] >> 16))    + b2f((ushortT)(pc_[j] >> 16));
                dst[j] = pk2(lo, hi);
            }
        }
    }
    __syncthreads();   // (3)

    // ==== Phase D': s_out1 normbuf K-steps (ks 9,10) + epilogue ====
    {
        const int e0 = ln, e1 = 16 + ln;
        #pragma unroll
        for (int ks = 9; ks < 11; ++ks) {
            short8 a0 = *(const short8*)(normbuf + e0 * 72 + (ks - 9) * 32 + klq);
            short8 a1 = *(const short8*)(normbuf + e1 * 72 + (ks - 9) * 32 + klq);
            short8 b0 = *(const short8*)(b0p + ks * 32);
            short8 b1 = *(const short8*)(b1p + ks * 32);
            acc00 = MFMA(a0, b0, acc00); acc01 = MFMA(a0, b1, acc01);
            acc10 = MFMA(a1, b0, acc10); acc11 = MFMA(a1, b1, acc11);
        }
        if (prt) {
            #pragma unroll
            for (int r = 0; r < 4; ++r) {
                int m0 = lq * 4 + r;
                float p00 = b2f(m2[m0 * 168 + dn0]);
                float p01 = b2f(m2[m0 * 168 + dn1]);
                float p10 = b2f(m2[(16 + m0) * 168 + dn0]);
                float p11 = b2f(m2[(16 + m0) * 168 + dn1]);
                m2[m0 * 168 + dn0]        = f2b(siluf_(acc00[r] + p00 + dbi0));
                m2[m0 * 168 + dn1]        = f2b(siluf_(acc01[r] + p01 + dbi1));
                m2[(16 + m0) * 168 + dn0] = f2b(siluf_(acc10[r] + p10 + dbi0));
                m2[(16 + m0) * 168 + dn1] = f2b(siluf_(acc11[r] + p11 + dbi1));
            }
        } else {
            #pragma unroll
            for (int r = 0; r < 4; ++r) {
                int m0 = lq * 4 + r;
                m2[m0 * 168 + dn0]        = f2b(siluf_(acc00[r] + dbi0));
                m2[m0 * 168 + dn1]        = f2b(siluf_(acc01[r] + dbi1));
                m2[(16 + m0) * 168 + dn0] = f2b(siluf_(acc10[r] + dbi0));
                m2[(16 + m0) * 168 + dn1] = f2b(siluf_(acc11[r] + dbi1));
            }
        }
    }
    __syncthreads();   // (4)

    // ==== Phase E+G (wave-local) ====
    float v1reg[2][4] = {{0.f,0.f,0.f,0.f},{0.f,0.f,0.f,0.f}};
    {
        f32x4 gacc = {0,0,0,0};
        {
            const ushortT* ap = m2 + (p * 16 + ln) * 168;
            const ushortT* bp = W1gT + ln * 128;
            #pragma unroll
            for (int ks = 0; ks < 4; ++ks)
                gacc = MFMA(*(const short8*)(ap + ks * 32 + lq * 8),
                            *(const short8*)(bp + ks * 32 + lq * 8), gacc);
        }
        float g1[4];
        {
            float bi = b1g[ln];
            #pragma unroll
            for (int r = 0; r < 4; ++r) g1[r] = sigmoidf_(gacc[r] + bi);
        }
        const ushortT* bpu = W1upT + ln * 64 + lq * 8;
        short8 bu1 = *(const short8*)bpu;
        short8 bu2 = *(const short8*)(bpu + 32);
        #pragma unroll
        for (int c = 0; c < 2; ++c) {
            if (c == 1 && w >= 2) break;
            int mt = w + c * 4;
            const ushortT* ap = vhidA + (mt * 16 + ln) * 40 + lq * 8;
            f32x4 acc = {0,0,0,0};
            acc = MFMA(*(const short8*)ap, bu1, acc);
            short8 a2 = {0, 0, 0, 0, 0, 0, 0, 0};
            if (lq == 0) a2 = *(const short8*)(ap + 32);
            acc = MFMA(a2, bu2, acc);
            #pragma unroll
            for (int r = 0; r < 4; ++r) {
                int row = mt * 16 + lq * 4 + r;
                float vv = acc[r] * g1[r];
                v1reg[c][r] = vv;
                v1s[row * 16 + ln] = f2b(vv);
            }
        }
        #pragma unroll
        for (int c = 0; c < 2; ++c) {
            if (c == 1 && w >= 2) break;
            int mt = w + c * 4;
            const ushortT* ap = v1s + (mt * 16 + ln) * 16 + lq * 8;
            short8 a = {0, 0, 0, 0, 0, 0, 0, 0};
            if (lq < 2) a = *(const short8*)ap;
            #pragma unroll
            for (int nt = 0; nt < 2; ++nt) {
                const ushortT* bp = W2dfT + (nt * 16 + ln) * 32 + lq * 8;
                f32x4 acc = {0,0,0,0};
                acc = MFMA(a, *(const short8*)bp, acc);
                if (nt == 0) {
                    ushortT* op = vhid2A + (mt * 16 + lq * 4) * 16 + ln;
                    op[0]  = f2b(acc[0]); op[16] = f2b(acc[1]);
                    op[32] = f2b(acc[2]); op[48] = f2b(acc[3]);
                } else if (ln < 3) {
                    float* op = vfr2f + (mt * 16 + lq * 4) * 3 + ln;
                    op[0] = acc[0]; op[3] = acc[1]; op[6] = acc[2]; op[9] = acc[3];
                }
            }
        }
    }
    __syncthreads();   // (5)

    // ==== Phase H: norm2 + local2 + zero pad into m2 cols 128..159 ====
    {
        #pragma unroll
        for (int k = 0; k < 2; ++k) {
            int i = t + k * 256, e = i >> 4, h = i & 15;
            float a0 = b2f(vhid2A[e * 16 + h]);
            float a1 = b2f(vhid2A[(32 + e) * 16 + h]);
            float a2 = b2f(vhid2A[(64 + e) * 16 + h]);
            m2[e * 168 + 128 + h] = f2b(sqrtf(fmaf(a0, a0, fmaf(a1, a1, fmaf(a2, a2, 1e-8f)))));
        }
        for (int i = t; i < 288; i += 256) {
            int e = i / 9, r = i - e * 9, a = r / 3, b = r - a * 3;
            float x = fr[e * 9 + b * 3 + 0] * vfr2f[e * 3 + a]
                    + fr[e * 9 + b * 3 + 1] * vfr2f[(32 + e) * 3 + a]
                    + fr[e * 9 + b * 3 + 2] * vfr2f[(64 + e) * 3 + a];
            m2[e * 168 + 144 + r] = f2b(x);
        }
        if (tj) m2[te * 168 + 152 + tj] = 0;
    }
    __syncthreads();   // (6)

    // ==== Phase I: s_out2 = m2[32][160] @ W2soT -> s2s (silu) ====
    {
        f32x4 acc00i = {0,0,0,0}, acc01i = {0,0,0,0}, acc10i = {0,0,0,0}, acc11i = {0,0,0,0};
        const ushortT* a0p = m2 + ln * 168 + lq * 8;
        const ushortT* a1p = m2 + (16 + ln) * 168 + lq * 8;
        const ushortT* b0pi = W2T + (w * 32 + ln) * 160 + lq * 8;
        const ushortT* b1pi = W2T + (w * 32 + 16 + ln) * 160 + lq * 8;
        #pragma unroll
        for (int ks = 0; ks < 5; ++ks) {
            short8 a0 = *(const short8*)(a0p + ks * 32);
            short8 a1 = *(const short8*)(a1p + ks * 32);
            short8 b0 = *(const short8*)(b0pi + ks * 32);
            short8 b1 = *(const short8*)(b1pi + ks * 32);
            acc00i = MFMA(a0, b0, acc00i); acc01i = MFMA(a0, b1, acc01i);
            acc10i = MFMA(a1, b0, acc10i); acc11i = MFMA(a1, b1, acc11i);
        }
        const int n0 = w * 32 + ln, n1 = n0 + 16;
        float bi0 = b2so[n0], bi1 = b2so[n1];
        #pragma unroll
        for (int r = 0; r < 4; ++r) {
            int m0 = lq * 4 + r;
            s2s[m0 * 136 + n0]        = f2b(siluf_(acc00i[r] + bi0));
            s2s[m0 * 136 + n1]        = f2b(siluf_(acc01i[r] + bi1));
            s2s[(16 + m0) * 136 + n0] = f2b(siluf_(acc10i[r] + bi0));
            s2s[(16 + m0) * 136 + n1] = f2b(siluf_(acc11i[r] + bi1));
        }
    }
    __syncthreads();   // (7)

    // ==== Phase J (wave-local) + attention ====
    {
        f32x4 gacc = {0,0,0,0};
        {
            const ushortT* ap = s2s + (p * 16 + ln) * 136;
            const ushortT* bp = W2gT + ln * 128;
            #pragma unroll
            for (int ks = 0; ks < 4; ++ks)
                gacc = MFMA(*(const short8*)(ap + ks * 32 + lq * 8),
                            *(const short8*)(bp + ks * 32 + lq * 8), gacc);
        }
        float g2[4];
        {
            float bi = b2g[ln];
            #pragma unroll
            for (int r = 0; r < 4; ++r) g2[r] = sigmoidf_(gacc[r] + bi);
        }
        const ushortT* bpu = W2upT + ln * 32 + lq * 8;
        short8 bu = *(const short8*)bpu;
        #pragma unroll
        for (int c = 0; c < 2; ++c) {
            if (c == 1 && w >= 2) break;
            int mt = w + c * 4;
            const ushortT* ap = vhid2A + (mt * 16 + ln) * 16 + lq * 8;
            short8 a = {0, 0, 0, 0, 0, 0, 0, 0};
            if (lq < 2) a = *(const short8*)ap;
            f32x4 acc = {0,0,0,0};
            acc = MFMA(a, bu, acc);
            #pragma unroll
            for (int r = 0; r < 4; ++r) {
                int row = mt * 16 + lq * 4 + r;
                float vfin = v1reg[c][r] + acc[r] * g2[r];
                v1f[row * 16 + ln] = f2b(vfin);
            }
        }
        {
            float sum = 0.f;
            int c0 = tj * 16;
            #pragma unroll
            for (int c = c0; c < c0 + 16; ++c)
                sum = fmaf(b2f(m2[te * 168 + c]) + b2f(s2s[te * 136 + c]), attW[c], sum);
            sum += __shfl_xor(sum, 4);
            sum += __shfl_xor(sum, 2);
            sum += __shfl_xor(sum, 1);
            att_reg = sigmoidf_(sum + attb[0]);
        }
    }
    __syncthreads();   // (8)

    // ==== Phase L: per-edge output ====
    {
        const float at = att_reg;
        if (csr) {
            const int pos = __shfl(posr, lane & 56);
            ushortT* fbe = fb + (size_t)pos * 176;
            #pragma unroll
            for (int k = 0; k < 11; ++k) {
                int j = 2 * tj + 16 * k;
                float v0, v1;
                if (j < 128) {
                    v0 = (b2f(m2[te * 168 + j])     + b2f(s2s[te * 136 + j]))     * at;
                    v1 = (b2f(m2[te * 168 + j + 1]) + b2f(s2s[te * 136 + j + 1])) * at;
                } else {
                    int r = j - 128;
                    int o0 = r / 3,        sp0 = r - o0 * 3;
                    int o1 = (r + 1) / 3,  sp1 = (r + 1) - o1 * 3;
                    v0 = b2f(v1f[(sp0 * 32 + te) * 16 + o0]);
                    v1 = b2f(v1f[(sp1 * 32 + te) * 16 + o1]);
                }
                *(uintT*)(fbe + j) = pk2(v0, v1);
            }
        } else {
            const int orow = nrT * 176;
            #pragma unroll
            for (int k = 0; k < 22; ++k) {
                int j = tj + k * 8;
                float val;
                if (j < 128) {
                    val = (b2f(m2[te * 168 + j]) + b2f(s2s[te * 136 + j])) * at;
                } else {
                    int r = j - 128, o = r / 3, sp = r - o * 3;
                    val = b2f(v1f[(sp * 32 + te) * 16 + o]);
                }
                atomicAdd(&out[orow + j], val);
            }
        }
    }
}

extern "C" void kernel_launch(void* const* d_in, const int* in_sizes, int n_in,
                              void* d_out, int out_size, void* d_ws, size_t ws_size,
                              hipStream_t stream) {
    const float* node_s = (const float*)d_in[0];
    const float* node_v = (const float*)d_in[1];
    const float* edge_s = (const float*)d_in[2];
    const float* edge_v = (const float*)d_in[3];
    const float* frames = (const float*)d_in[4];
    const float* W1d  = (const float*)d_in[5];
    const float* W1f  = (const float*)d_in[6];
    const float* W1so = (const float*)d_in[7];
    const float* b1so = (const float*)d_in[8];
    const float* W1up = (const float*)d_in[9];
    const float* W1g  = (const float*)d_in[10];
    const float* b1g  = (const float*)d_in[11];
    const float* W2d  = (const float*)d_in[12];
    const float* W2f  = (const float*)d_in[13];
    const float* W2so = (const float*)d_in[14];
    const float* b2so = (const float*)d_in[15];
    const float* W2up = (const float*)d_in[16];
    const float* W2g  = (const float*)d_in[17];
    const float* b2g  = (const float*)d_in[18];
    const float* attW = (const float*)d_in[19];
    const float* attb = (const float*)d_in[20];
    const void*  eidx = d_in[21];

    float* out = (float*)d_out;
    char* ws = (char*)d_ws;

    const int csr = ws_size >= WS_CSR;
    ushortT* wt    = csr ? (ushortT*)(ws + WT_OFF)  : (ushortT*)ws;
    ushortT* fbuf  = csr ? (ushortT*)ws             : nullptr;
    int*     noff  = csr ? (int*)(ws + NOFF_OFF)    : nullptr;
    int*     cur   = csr ? (int*)(ws + CUR_OFF)     : nullptr;
    const int pre  = csr && (ws_size >= PRE_END);
    ushortT* prt   = pre ? (ushortT*)(ws + PR_OFF) : nullptr;
    ushortT* pct   = pre ? (ushortT*)(ws + PC_OFF) : nullptr;

    if (csr) {
        hipMemsetAsync(cur, 0, NN * sizeof(int), stream);
        setup_kernel<<<pre ? 782 : 625, 256, 0, stream>>>(
            W1so, W2so, W1d, W1f, W1g, W1up, W2d, W2f, W2g, W2up,
            wt, eidx, cur, node_s, prt, pct);
        scan_kernel<<<1, 256, 0, stream>>>(cur, noff);
    } else {
        prep_kernel<<<294, 256, 0, stream>>>(W1so, W2so, W1d, W1f, W1g, W1up,
                                             W2d, W2f, W2g, W2up, wt, out);
    }

    edge_kernel<<<E_TOT / EPB, 256, 0, stream>>>(
        node_s, node_v, edge_s, edge_v, frames,
        b1so, b1g, b2so, b2g, attW, attb,
        (const ushortT*)wt, eidx, out, fbuf, cur, noff,
        nullptr, prt, pct, csr);

    if (csr) {
        node_kernel<<<2500, 256, 0, stream>>>((const ushortT*)fbuf, noff, out);
    }
}